// Round 1
// baseline (5053.274 us; speedup 1.0000x reference)
//
#include <hip/hip_runtime.h>
#include <math.h>

#define NINST 4096

// ---------------------------------------------------------------------------
// Fused conv1(4x4)+relu+pool2 + conv2(3x3)+relu+pool2, one block per instance.
// x:(N,3,32,32) -> emb:(N,1728)   [flatten order c*36 + y*6 + x]
// LDS: x 12KB + w1 6.9KB + h1 28.2KB + w2chunk 15.6KB = ~63KB -> 2 blocks/CU
// ---------------------------------------------------------------------------
__launch_bounds__(256)
__global__ void conv_fused(const float* __restrict__ x,
                           const float* __restrict__ w1, const float* __restrict__ b1,
                           const float* __restrict__ w2, const float* __restrict__ b2,
                           float* __restrict__ emb) {
  __shared__ __align__(16) float x_s[3072];    // 3*32*32
  __shared__ __align__(16) float w1_s[1728];   // 36*3*4*4
  __shared__ __align__(16) float h1_s[7056];   // 36*14*14
  __shared__ __align__(16) float w2c[3888];    // 48 oc * 9 ic * 9

  const int n = blockIdx.x;
  const int tid = threadIdx.x;

  // stage x and w1 (float4)
  {
    const float4* xg = (const float4*)(x + (size_t)n * 3072);
    float4* xs4 = (float4*)x_s;
#pragma unroll
    for (int i = 0; i < 3; i++) xs4[tid + 256 * i] = xg[tid + 256 * i];
    const float4* wg = (const float4*)w1;
    float4* ws4 = (float4*)w1_s;
    ws4[tid] = wg[tid];
    if (tid < 176) ws4[256 + tid] = wg[256 + tid];   // 432 float4 total
  }
  __syncthreads();

  // ---- conv1 + relu + pool: 36*14*14 = 7056 pooled outputs ----
  for (int o = tid; o < 7056; o += 256) {
    const int oc = o / 196;
    const int rem = o - oc * 196;
    const int pr = rem / 14;
    const int pc = rem - pr * 14;
    const int y0 = pr * 2, xx0 = pc * 2;
    float a0 = 0.f, a1 = 0.f, a2 = 0.f, a3 = 0.f;
#pragma unroll
    for (int ic = 0; ic < 3; ic++) {
      float patch[5][6];
#pragma unroll
      for (int yy = 0; yy < 5; yy++) {
        const float2* row = (const float2*)&x_s[ic * 1024 + (y0 + yy) * 32 + xx0];
        float2 p0 = row[0], p1 = row[1], p2 = row[2];
        patch[yy][0] = p0.x; patch[yy][1] = p0.y; patch[yy][2] = p1.x;
        patch[yy][3] = p1.y; patch[yy][4] = p2.x; patch[yy][5] = p2.y;
      }
      const float4* w4 = (const float4*)&w1_s[oc * 48 + ic * 16];
      float4 wA = w4[0], wB = w4[1], wC = w4[2], wD = w4[3];
      const float wv[16] = {wA.x, wA.y, wA.z, wA.w, wB.x, wB.y, wB.z, wB.w,
                            wC.x, wC.y, wC.z, wC.w, wD.x, wD.y, wD.z, wD.w};
#pragma unroll
      for (int ky = 0; ky < 4; ky++)
#pragma unroll
        for (int kx = 0; kx < 4; kx++) {
          const float w = wv[ky * 4 + kx];
          a0 = fmaf(w, patch[ky][kx], a0);
          a1 = fmaf(w, patch[ky][kx + 1], a1);
          a2 = fmaf(w, patch[ky + 1][kx], a2);
          a3 = fmaf(w, patch[ky + 1][kx + 1], a3);
        }
    }
    const float v = fmaxf(fmaxf(a0, a1), fmaxf(a2, a3)) + b1[oc];
    h1_s[o] = fmaxf(v, 0.f);
  }

  // ---- conv2 + relu + pool: 48*6*6 = 1728 pooled outputs, 4 ic-chunks of 9 ----
  float acc[7][4];
#pragma unroll
  for (int u = 0; u < 7; u++)
#pragma unroll
    for (int q = 0; q < 4; q++) acc[u][q] = 0.f;

  for (int c = 0; c < 4; c++) {
    __syncthreads();   // h1 ready (c==0) / previous chunk compute done
    for (int i = tid; i < 3888; i += 256) {
      const int oc = i / 81;
      const int r = i - oc * 81;
      w2c[i] = w2[oc * 324 + c * 81 + r];
    }
    __syncthreads();
#pragma unroll
    for (int u = 0; u < 7; u++) {
      const int o = tid + 256 * u;
      if (o < 1728) {
        const int oc = o / 36;
        const int rem = o - oc * 36;
        const int pr = rem / 6, pc = rem - pr * 6;
        const int y0 = pr * 2, x0c = pc * 2;
        const float* wbase = &w2c[oc * 81];
#pragma unroll
        for (int icl = 0; icl < 9; icl++) {
          float patch[4][4];
#pragma unroll
          for (int yy = 0; yy < 4; yy++) {
            const float2* row =
                (const float2*)&h1_s[(c * 9 + icl) * 196 + (y0 + yy) * 14 + x0c];
            float2 p0 = row[0], p1 = row[1];
            patch[yy][0] = p0.x; patch[yy][1] = p0.y;
            patch[yy][2] = p1.x; patch[yy][3] = p1.y;
          }
          const float* wr = wbase + icl * 9;
#pragma unroll
          for (int ky = 0; ky < 3; ky++)
#pragma unroll
            for (int kx = 0; kx < 3; kx++) {
              const float w = wr[ky * 3 + kx];
              acc[u][0] = fmaf(w, patch[ky][kx], acc[u][0]);
              acc[u][1] = fmaf(w, patch[ky][kx + 1], acc[u][1]);
              acc[u][2] = fmaf(w, patch[ky + 1][kx], acc[u][2]);
              acc[u][3] = fmaf(w, patch[ky + 1][kx + 1], acc[u][3]);
            }
        }
      }
    }
  }

#pragma unroll
  for (int u = 0; u < 7; u++) {
    const int o = tid + 256 * u;
    if (o < 1728) {
      const int oc = o / 36;
      const float v =
          fmaxf(fmaxf(acc[u][0], acc[u][1]), fmaxf(acc[u][2], acc[u][3])) + b2[oc];
      emb[(size_t)n * 1728 + o] = fmaxf(v, 0.f);
    }
  }
}

// ---------------------------------------------------------------------------
// C[m,n] = act( sum_k A[m,k]*B[n,k] + bias[n] )   (B row-major (N,K) = B^T GEMM)
// 64x64 tile, BK=16, 256 threads, 4x4 micro-tile. ACT: 0=none 1=relu 2=tanh
// All dims must be multiples of 64 (K multiple of 16) — true for all calls.
// ---------------------------------------------------------------------------
template <int ACT>
__launch_bounds__(256)
__global__ void gemm_bt(const float* __restrict__ A, const float* __restrict__ B,
                        const float* __restrict__ bias, float* __restrict__ C,
                        int K, int lda, int ldb, int ldc) {
  __shared__ __align__(16) float As[16][68];
  __shared__ __align__(16) float Bs[16][68];
  const int tid = threadIdx.x;
  const int tx = tid & 15, ty = tid >> 4;
  const int m0 = blockIdx.y * 64, n0 = blockIdx.x * 64;
  const int lr = tid >> 2;          // tile row (0..63)
  const int lc = (tid & 3) << 2;    // k-chunk col (0,4,8,12)
  const float* Ap = A + (size_t)(m0 + lr) * lda + lc;
  const float* Bp = B + (size_t)(n0 + lr) * ldb + lc;
  float acc[4][4];
#pragma unroll
  for (int i = 0; i < 4; i++)
#pragma unroll
    for (int j = 0; j < 4; j++) acc[i][j] = 0.f;

  for (int k0 = 0; k0 < K; k0 += 16) {
    const float4 av = *(const float4*)(Ap + k0);
    const float4 bv = *(const float4*)(Bp + k0);
    __syncthreads();
    As[lc + 0][lr] = av.x; As[lc + 1][lr] = av.y;
    As[lc + 2][lr] = av.z; As[lc + 3][lr] = av.w;
    Bs[lc + 0][lr] = bv.x; Bs[lc + 1][lr] = bv.y;
    Bs[lc + 2][lr] = bv.z; Bs[lc + 3][lr] = bv.w;
    __syncthreads();
#pragma unroll
    for (int k = 0; k < 16; k++) {
      const float4 a = *(const float4*)&As[k][ty << 2];
      const float4 b = *(const float4*)&Bs[k][tx << 2];
      const float ar[4] = {a.x, a.y, a.z, a.w};
      const float br[4] = {b.x, b.y, b.z, b.w};
#pragma unroll
      for (int i = 0; i < 4; i++)
#pragma unroll
        for (int j = 0; j < 4; j++) acc[i][j] = fmaf(ar[i], br[j], acc[i][j]);
    }
  }

  const float4 bb = *(const float4*)&bias[n0 + (tx << 2)];
  const float bbr[4] = {bb.x, bb.y, bb.z, bb.w};
#pragma unroll
  for (int r = 0; r < 4; r++) {
    float o_[4];
#pragma unroll
    for (int j = 0; j < 4; j++) {
      float v = acc[r][j] + bbr[j];
      if (ACT == 1) v = fmaxf(v, 0.f);
      if (ACT == 2) v = tanhf(v);
      o_[j] = v;
    }
    float4 ov = make_float4(o_[0], o_[1], o_[2], o_[3]);
    *(float4*)&C[(size_t)(m0 + (ty << 2) + r) * ldc + n0 + (tx << 2)] = ov;
  }
}

// ---------------------------------------------------------------------------
// Neighborhood attention: one wave per instance. <=8 grid neighbors.
// H lives in H2[:, :512]; writes nbhd into H2[:, 512:1024].
// ---------------------------------------------------------------------------
__launch_bounds__(256)
__global__ void nbhd_k(float* __restrict__ H2, const float* __restrict__ T) {
  const int wid = (blockIdx.x * 256 + threadIdx.x) >> 6;   // instance
  const int lane = threadIdx.x & 63;
  const int r = wid >> 6, c = wid & 63;
  const float* hi = H2 + (size_t)wid * 1024;
  float hreg[8];
#pragma unroll
  for (int u = 0; u < 8; u++) hreg[u] = hi[u * 64 + lane];

  float sv[8];
  int jv[8];
  bool ok[8];
  int q = 0;
#pragma unroll
  for (int dr = -1; dr <= 1; dr++)
#pragma unroll
    for (int dc = -1; dc <= 1; dc++) {
      if (dr == 0 && dc == 0) continue;
      const int rr = r + dr, cc = c + dc;
      const bool v = (rr >= 0) && (rr < 64) && (cc >= 0) && (cc < 64);
      const int j = v ? (rr * 64 + cc) : wid;
      const float* tj = T + (size_t)j * 512;
      float s = 0.f;
#pragma unroll
      for (int u = 0; u < 8; u++) s = fmaf(hreg[u], tj[u * 64 + lane], s);
#pragma unroll
      for (int off = 32; off > 0; off >>= 1) s += __shfl_xor(s, off, 64);
      sv[q] = v ? s : -3.4e38f;
      jv[q] = j;
      ok[q] = v;
      q++;
    }

  float m = sv[0];
#pragma unroll
  for (int i = 1; i < 8; i++) m = fmaxf(m, sv[i]);
  float e[8], den = 0.f;
#pragma unroll
  for (int i = 0; i < 8; i++) {
    e[i] = ok[i] ? expf(sv[i] - m) : 0.f;
    den += e[i];
  }
  const float inv = 1.f / den;

  float outv[8];
#pragma unroll
  for (int u = 0; u < 8; u++) outv[u] = 0.f;
#pragma unroll
  for (int i = 0; i < 8; i++) {
    const float al = e[i] * inv;
    const float* hj = H2 + (size_t)jv[i] * 1024;
#pragma unroll
    for (int u = 0; u < 8; u++) outv[u] = fmaf(al, hj[u * 64 + lane], outv[u]);
  }
  float* dst = H2 + (size_t)wid * 1024 + 512;
#pragma unroll
  for (int u = 0; u < 8; u++) dst[u * 64 + lane] = outv[u];
}

// ---------------------------------------------------------------------------
// tl[t,n] = P[n,:] . templates[t,:]   (one wave per instance)
// ---------------------------------------------------------------------------
__launch_bounds__(256)
__global__ void templ_scores(const float* __restrict__ P, const float* __restrict__ tmpl,
                             float* __restrict__ tl) {
  const int wid = (blockIdx.x * 256 + threadIdx.x) >> 6;
  const int lane = threadIdx.x & 63;
  const float* p = P + (size_t)wid * 1024;
  float pr[16];
#pragma unroll
  for (int u = 0; u < 16; u++) pr[u] = p[u * 64 + lane];
  for (int t = 0; t < 10; t++) {
    const float* tp = tmpl + t * 1024;
    float s = 0.f;
#pragma unroll
    for (int u = 0; u < 16; u++) s = fmaf(pr[u], tp[u * 64 + lane], s);
#pragma unroll
    for (int off = 32; off > 0; off >>= 1) s += __shfl_xor(s, off, 64);
    if (lane == 0) tl[t * NINST + wid] = s;
  }
}

// ---------------------------------------------------------------------------
// Per-template softmax over N=4096 (one block per template)
// ---------------------------------------------------------------------------
__launch_bounds__(256)
__global__ void softmax_rows(const float* __restrict__ tl, float* __restrict__ betas) {
  const int t = blockIdx.x, tid = threadIdx.x;
  __shared__ float red[256];
  const float* row = tl + t * NINST;
  float m = -3.4e38f;
  for (int i = tid; i < NINST; i += 256) m = fmaxf(m, row[i]);
  red[tid] = m;
  __syncthreads();
  for (int s = 128; s > 0; s >>= 1) {
    if (tid < s) red[tid] = fmaxf(red[tid], red[tid + s]);
    __syncthreads();
  }
  m = red[0];
  __syncthreads();
  float sum = 0.f;
  for (int i = tid; i < NINST; i += 256) sum += expf(row[i] - m);
  red[tid] = sum;
  __syncthreads();
  for (int s = 128; s > 0; s >>= 1) {
    if (tid < s) red[tid] += red[tid + s];
    __syncthreads();
  }
  const float inv = 1.f / red[0];
  for (int i = tid; i < NINST; i += 256) betas[t * NINST + i] = expf(row[i] - m) * inv;
}

// ---------------------------------------------------------------------------
// embs[t,k] = sum_n betas[t,n] * H2[n,k]    grid (4 k-chunks, 10 templates)
// ---------------------------------------------------------------------------
__launch_bounds__(256)
__global__ void embs_k(const float* __restrict__ betas, const float* __restrict__ H2,
                       float* __restrict__ embs) {
  const int t = blockIdx.y;
  const int k = blockIdx.x * 256 + threadIdx.x;
  const float* br = betas + t * NINST;
  float a = 0.f;
  for (int n = 0; n < NINST; n++) a = fmaf(br[n], H2[(size_t)n * 1024 + k], a);
  embs[t * 1024 + k] = a;
}

// ---------------------------------------------------------------------------
// Global attention tail: g, gammas, M, Y_prob, Y_hat. Single block.
// out[0]=Y_prob, out[1]=Y_hat; gammas stored to ws for the A kernel.
// ---------------------------------------------------------------------------
__launch_bounds__(256)
__global__ void ga_k(const float* __restrict__ embs_g, const float* __restrict__ ga1_w,
                     const float* __restrict__ ga1_b, const float* __restrict__ ga2_w,
                     const float* __restrict__ ga2_b, const float* __restrict__ cls_w,
                     const float* __restrict__ cls_b, float* __restrict__ out,
                     float* __restrict__ gammas_ws) {
  __shared__ __align__(16) float embs_s[10 * 1024];
  __shared__ float hh[10 * 128];
  __shared__ float red[256];
  __shared__ float g_s[10], gam_s[10];
  __shared__ float M_s[1024];
  const int tid = threadIdx.x;
  const int wave = tid >> 6, lane = tid & 63;

  for (int i = tid; i < 10240; i += 256) embs_s[i] = embs_g[i];
  __syncthreads();

  // hh[t,d] = tanh(embs[t,:].ga1_w[d,:] + ga1_b[d])
  for (int j = 0; j < 32; j++) {
    const int d = wave * 32 + j;
    float wreg[16];
#pragma unroll
    for (int u = 0; u < 16; u++) wreg[u] = ga1_w[(size_t)d * 1024 + u * 64 + lane];
    const float bd = ga1_b[d];
    for (int t = 0; t < 10; t++) {
      float s = 0.f;
#pragma unroll
      for (int u = 0; u < 16; u++) s = fmaf(wreg[u], embs_s[t * 1024 + u * 64 + lane], s);
#pragma unroll
      for (int off = 32; off > 0; off >>= 1) s += __shfl_xor(s, off, 64);
      if (lane == 0) hh[t * 128 + d] = tanhf(s + bd);
    }
  }
  __syncthreads();

  // g[t] = hh[t,:].ga2_w + ga2_b
  if (wave == 0) {
    for (int t = 0; t < 10; t++) {
      float s = hh[t * 128 + lane] * ga2_w[lane] + hh[t * 128 + 64 + lane] * ga2_w[64 + lane];
#pragma unroll
      for (int off = 32; off > 0; off >>= 1) s += __shfl_xor(s, off, 64);
      if (lane == 0) g_s[t] = s + ga2_b[0];
    }
  }
  __syncthreads();

  if (tid == 0) {
    float m = g_s[0];
    for (int t = 1; t < 10; t++) m = fmaxf(m, g_s[t]);
    float sum = 0.f;
    for (int t = 0; t < 10; t++) sum += expf(g_s[t] - m);
    for (int t = 0; t < 10; t++) {
      gam_s[t] = expf(g_s[t] - m) / sum;
      gammas_ws[t] = gam_s[t];
    }
  }
  __syncthreads();

  // M[k] = sum_t gam[t]*embs[t,k]
  for (int k = tid; k < 1024; k += 256) {
    float a = 0.f;
#pragma unroll
    for (int t = 0; t < 10; t++) a = fmaf(gam_s[t], embs_s[t * 1024 + k], a);
    M_s[k] = a;
  }
  __syncthreads();

  float part = 0.f;
  for (int k = tid; k < 1024; k += 256) part = fmaf(M_s[k], cls_w[k], part);
  red[tid] = part;
  __syncthreads();
  for (int s = 128; s > 0; s >>= 1) {
    if (tid < s) red[tid] += red[tid + s];
    __syncthreads();
  }
  if (tid == 0) {
    const float z = red[0] + cls_b[0];
    const float yp = 1.f / (1.f + expf(-z));
    out[0] = yp;
    out[1] = (yp >= 0.5f) ? 1.f : 0.f;
  }
}

// ---------------------------------------------------------------------------
// A[n] = sum_t gammas[t] * betas[t,n]
// ---------------------------------------------------------------------------
__launch_bounds__(256)
__global__ void a_k(const float* __restrict__ betas, const float* __restrict__ gam,
                    float* __restrict__ outA) {
  const int n = blockIdx.x * 256 + threadIdx.x;
  float a = 0.f;
#pragma unroll
  for (int t = 0; t < 10; t++) a = fmaf(gam[t], betas[t * NINST + n], a);
  outA[n] = a;
}

// ---------------------------------------------------------------------------
extern "C" void kernel_launch(void* const* d_in, const int* in_sizes, int n_in,
                              void* d_out, int out_size, void* d_ws, size_t ws_size,
                              hipStream_t stream) {
  const float* x       = (const float*)d_in[0];
  // d_in[1] = positions (int32) — derivable from instance index, unused
  const float* w1      = (const float*)d_in[2];
  const float* b1      = (const float*)d_in[3];
  const float* w2      = (const float*)d_in[4];
  const float* b2      = (const float*)d_in[5];
  const float* fc1_w   = (const float*)d_in[6];
  const float* fc1_b   = (const float*)d_in[7];
  const float* fc2_w   = (const float*)d_in[8];
  const float* fc2_b   = (const float*)d_in[9];
  const float* nbr_w   = (const float*)d_in[10];
  const float* nbr_b   = (const float*)d_in[11];
  const float* tmpl    = (const float*)d_in[12];
  const float* proto_w = (const float*)d_in[13];
  const float* proto_b = (const float*)d_in[14];
  const float* ga1_w   = (const float*)d_in[15];
  const float* ga1_b   = (const float*)d_in[16];
  const float* ga2_w   = (const float*)d_in[17];
  const float* ga2_b   = (const float*)d_in[18];
  const float* cls_w   = (const float*)d_in[19];
  const float* cls_b   = (const float*)d_in[20];
  float* out = (float*)d_out;

  float* ws   = (float*)d_ws;
  float* emb  = ws;                      // 4096*1728 = 7,077,888
  float* H2   = emb + 4096 * 1728;       // 4096*1024 (cols 0..511 = H, 512.. = nbhd)
  float* H1   = H2 + 4096 * 1024;        // 4096*512
  float* Tb   = H1 + 4096 * 512;         // 4096*512
  float* P    = Tb + 4096 * 512;         // 4096*1024
  float* tl   = P + 4096 * 1024;         // 10*4096
  float* bet  = tl + 10 * NINST;         // 10*4096
  float* embs = bet + 10 * NINST;        // 10*1024
  float* gam  = embs + 10 * 1024;        // 10

  conv_fused<<<NINST, 256, 0, stream>>>(x, w1, b1, w2, b2, emb);
  gemm_bt<1><<<dim3(8, 64), 256, 0, stream>>>(emb, fc1_w, fc1_b, H1, 1728, 1728, 1728, 512);
  gemm_bt<1><<<dim3(8, 64), 256, 0, stream>>>(H1, fc2_w, fc2_b, H2, 512, 512, 512, 1024);
  gemm_bt<2><<<dim3(8, 64), 256, 0, stream>>>(H2, nbr_w, nbr_b, Tb, 512, 1024, 512, 512);
  nbhd_k<<<1024, 256, 0, stream>>>(H2, Tb);
  gemm_bt<2><<<dim3(16, 64), 256, 0, stream>>>(H2, proto_w, proto_b, P, 1024, 1024, 1024, 1024);
  templ_scores<<<1024, 256, 0, stream>>>(P, tmpl, tl);
  softmax_rows<<<10, 256, 0, stream>>>(tl, bet);
  embs_k<<<dim3(4, 10), 256, 0, stream>>>(bet, H2, embs);
  ga_k<<<1, 256, 0, stream>>>(embs, ga1_w, ga1_b, ga2_w, ga2_b, cls_w, cls_b, out, gam);
  a_k<<<16, 256, 0, stream>>>(bet, gam, out + 2);
}

// Round 2
// 1208.028 us; speedup vs baseline: 4.1831x; 4.1831x over previous
//
#include <hip/hip_runtime.h>
#include <math.h>

#define NINST 4096

// ---------------------------------------------------------------------------
// Fused conv1(4x4)+relu+pool2 + conv2(3x3)+relu+pool2, one block per instance.
// x:(N,3,32,32) -> emb:(N,1728)   [flatten order oc*36 + py*6 + px]
//
// LDS layout (floats), total 12816 = 51.3KB -> 3 blocks/CU:
//   [0,    3888) overlay: x (3*32 rows, stride 34 = 3264) / w2 chunk (48*81)
//   [3888, 5688) w1 (36 oc, stride 50)
//   [5688,12816) h1 (36 ch, 14x14 rows stride 14, channel stride 198)
//
// conv1: thread = (oc 0..35, rp 0..6) -> pooled rows 2rp,2rp+1 (252 threads)
// conv2: thread = (ty -> 3 ocs, tx -> unpooled row 0..11), 2x2 pool via shfl
// ---------------------------------------------------------------------------
__launch_bounds__(256, 3)
__global__ void conv_fused(const float* __restrict__ x,
                           const float* __restrict__ w1, const float* __restrict__ b1,
                           const float* __restrict__ w2, const float* __restrict__ b2,
                           float* __restrict__ emb) {
  __shared__ __align__(16) float smem[12816];
  float* xw  = smem;          // x overlay w2-chunk
  float* w1s = smem + 3888;
  float* h1  = smem + 5688;

  const int n = blockIdx.x;
  const int tid = threadIdx.x;

  // ---- stage x (rows padded to 34) and w1 (oc stride 50) ----
  {
    const float2* xg = (const float2*)(x + (size_t)n * 3072);
    for (int i = tid; i < 1536; i += 256) {
      const int f = i * 2;
      const int ic = f >> 10, rem = f & 1023, yy = rem >> 5, xx = rem & 31;
      *(float2*)&xw[ic * 1088 + yy * 34 + xx] = xg[i];
    }
    for (int i = tid; i < 1728; i += 256) {
      const int oc = i / 48, r = i - oc * 48;
      w1s[oc * 50 + r] = w1[i];
    }
  }
  __syncthreads();

  // ---- conv1 + relu + pool -> h1 ----
  if (tid < 252) {
    const int oc = tid / 7, rp = tid % 7;
    const float bia = b1[oc];
#pragma unroll
    for (int rp2 = 0; rp2 < 2; rp2++) {
      const int pr = 2 * rp + rp2;
      float pm[14];
#pragma unroll
      for (int upy = 0; upy < 2; upy++) {
        const int y = 2 * pr + upy;
#pragma unroll
        for (int half = 0; half < 2; half++) {
          const int cb = half * 14;
          float ra[14];
#pragma unroll
          for (int c = 0; c < 14; c++) ra[c] = 0.f;
#pragma unroll
          for (int ic = 0; ic < 3; ic++) {
            float wv[16];
            {
              const float2* wp = (const float2*)&w1s[oc * 50 + ic * 16];
#pragma unroll
              for (int j = 0; j < 8; j++) {
                float2 t = wp[j];
                wv[2 * j] = t.x; wv[2 * j + 1] = t.y;
              }
            }
#pragma unroll
            for (int ky = 0; ky < 4; ky++) {
              float xr[18];
              const float2* rowp = (const float2*)&xw[ic * 1088 + (y + ky) * 34 + cb];
#pragma unroll
              for (int j = 0; j < 9; j++) {
                float2 t = rowp[j];
                xr[2 * j] = t.x; xr[2 * j + 1] = t.y;
              }
#pragma unroll
              for (int kx = 0; kx < 4; kx++) {
                const float w = wv[ky * 4 + kx];
#pragma unroll
                for (int c = 0; c < 14; c++) ra[c] = fmaf(w, xr[c + kx], ra[c]);
              }
            }
          }
#pragma unroll
          for (int c = 0; c < 7; c++) {
            const float v = fmaxf(ra[2 * c], ra[2 * c + 1]);
            const int pc = half * 7 + c;
            if (upy == 0) pm[pc] = v; else pm[pc] = fmaxf(pm[pc], v);
          }
        }
      }
#pragma unroll
      for (int c = 0; c < 7; c++) {
        float2 o;
        o.x = fmaxf(pm[2 * c] + bia, 0.f);
        o.y = fmaxf(pm[2 * c + 1] + bia, 0.f);
        *(float2*)&h1[oc * 198 + pr * 14 + 2 * c] = o;
      }
    }
  }

  // ---- conv2 + relu + pool ----
  const int ty = tid >> 4, tx = tid & 15;
  const bool act2 = (tx < 12);
  float acc[3][12];
#pragma unroll
  for (int j = 0; j < 3; j++)
#pragma unroll
    for (int q = 0; q < 12; q++) acc[j][q] = 0.f;

  for (int c = 0; c < 4; c++) {
    __syncthreads();   // h1 ready & x reads done (c==0) / prev chunk compute done
    for (int i = tid; i < 3888; i += 256) {
      const int oc = i / 81, r = i - oc * 81;
      xw[i] = w2[oc * 324 + c * 81 + r];
    }
    __syncthreads();
    if (act2) {
#pragma unroll
      for (int icl = 0; icl < 9; icl++) {
        const int ic = c * 9 + icl;
        float wr[3][9];
#pragma unroll
        for (int j = 0; j < 3; j++)
#pragma unroll
          for (int t = 0; t < 9; t++)
            wr[j][t] = xw[(ty * 3 + j) * 81 + icl * 9 + t];
#pragma unroll
        for (int ky = 0; ky < 3; ky++) {
          float xr[14];
          const float2* rowp = (const float2*)&h1[ic * 198 + (tx + ky) * 14];
#pragma unroll
          for (int j = 0; j < 7; j++) {
            float2 t = rowp[j];
            xr[2 * j] = t.x; xr[2 * j + 1] = t.y;
          }
#pragma unroll
          for (int kx = 0; kx < 3; kx++)
#pragma unroll
            for (int j = 0; j < 3; j++) {
              const float w = wr[j][ky * 3 + kx];
#pragma unroll
              for (int q = 0; q < 12; q++)
                acc[j][q] = fmaf(w, xr[q + kx], acc[j][q]);
            }
        }
      }
    }
  }

  __syncthreads();   // all h1 reads done; reuse h1 region as emb staging
  if (act2) {
#pragma unroll
    for (int j = 0; j < 3; j++) {
      const int oc = ty * 3 + j;
      const float bia = b2[oc];
#pragma unroll
      for (int q = 0; q < 6; q++) {
        const float m = fmaxf(acc[j][2 * q], acc[j][2 * q + 1]);
        const float o = __shfl_xor(m, 1, 64);
        if ((tx & 1) == 0) {
          h1[oc * 36 + (tx >> 1) * 6 + q] = fmaxf(fmaxf(m, o) + bia, 0.f);
        }
      }
    }
  }
  __syncthreads();
  {
    float4* dst = (float4*)(emb + (size_t)n * 1728);
    const float4* src = (const float4*)h1;
    for (int i = tid; i < 432; i += 256) dst[i] = src[i];
  }
}

// ---------------------------------------------------------------------------
// C[m,n] = act( sum_k A[m,k]*B[n,k] + bias[n] )   (B row-major (N,K) = B^T GEMM)
// 64x64 tile, BK=16, 256 threads, 4x4 micro-tile. ACT: 0=none 1=relu 2=tanh
// ---------------------------------------------------------------------------
template <int ACT>
__launch_bounds__(256)
__global__ void gemm_bt(const float* __restrict__ A, const float* __restrict__ B,
                        const float* __restrict__ bias, float* __restrict__ C,
                        int K, int lda, int ldb, int ldc) {
  __shared__ __align__(16) float As[16][68];
  __shared__ __align__(16) float Bs[16][68];
  const int tid = threadIdx.x;
  const int tx = tid & 15, ty = tid >> 4;
  const int m0 = blockIdx.y * 64, n0 = blockIdx.x * 64;
  const int lr = tid >> 2;          // tile row (0..63)
  const int lc = (tid & 3) << 2;    // k-chunk col (0,4,8,12)
  const float* Ap = A + (size_t)(m0 + lr) * lda + lc;
  const float* Bp = B + (size_t)(n0 + lr) * ldb + lc;
  float acc[4][4];
#pragma unroll
  for (int i = 0; i < 4; i++)
#pragma unroll
    for (int j = 0; j < 4; j++) acc[i][j] = 0.f;

  for (int k0 = 0; k0 < K; k0 += 16) {
    const float4 av = *(const float4*)(Ap + k0);
    const float4 bv = *(const float4*)(Bp + k0);
    __syncthreads();
    As[lc + 0][lr] = av.x; As[lc + 1][lr] = av.y;
    As[lc + 2][lr] = av.z; As[lc + 3][lr] = av.w;
    Bs[lc + 0][lr] = bv.x; Bs[lc + 1][lr] = bv.y;
    Bs[lc + 2][lr] = bv.z; Bs[lc + 3][lr] = bv.w;
    __syncthreads();
#pragma unroll
    for (int k = 0; k < 16; k++) {
      const float4 a = *(const float4*)&As[k][ty << 2];
      const float4 b = *(const float4*)&Bs[k][tx << 2];
      const float ar[4] = {a.x, a.y, a.z, a.w};
      const float br[4] = {b.x, b.y, b.z, b.w};
#pragma unroll
      for (int i = 0; i < 4; i++)
#pragma unroll
        for (int j = 0; j < 4; j++) acc[i][j] = fmaf(ar[i], br[j], acc[i][j]);
    }
  }

  const float4 bb = *(const float4*)&bias[n0 + (tx << 2)];
  const float bbr[4] = {bb.x, bb.y, bb.z, bb.w};
#pragma unroll
  for (int r = 0; r < 4; r++) {
    float o_[4];
#pragma unroll
    for (int j = 0; j < 4; j++) {
      float v = acc[r][j] + bbr[j];
      if (ACT == 1) v = fmaxf(v, 0.f);
      if (ACT == 2) v = tanhf(v);
      o_[j] = v;
    }
    float4 ov = make_float4(o_[0], o_[1], o_[2], o_[3]);
    *(float4*)&C[(size_t)(m0 + (ty << 2) + r) * ldc + n0 + (tx << 2)] = ov;
  }
}

// ---------------------------------------------------------------------------
// Neighborhood attention: one wave per instance. <=8 grid neighbors.
// H lives in H2[:, :512]; writes nbhd into H2[:, 512:1024].
// ---------------------------------------------------------------------------
__launch_bounds__(256)
__global__ void nbhd_k(float* __restrict__ H2, const float* __restrict__ T) {
  const int wid = (blockIdx.x * 256 + threadIdx.x) >> 6;   // instance
  const int lane = threadIdx.x & 63;
  const int r = wid >> 6, c = wid & 63;
  const float* hi = H2 + (size_t)wid * 1024;
  float hreg[8];
#pragma unroll
  for (int u = 0; u < 8; u++) hreg[u] = hi[u * 64 + lane];

  float sv[8];
  int jv[8];
  bool ok[8];
  int q = 0;
#pragma unroll
  for (int dr = -1; dr <= 1; dr++)
#pragma unroll
    for (int dc = -1; dc <= 1; dc++) {
      if (dr == 0 && dc == 0) continue;
      const int rr = r + dr, cc = c + dc;
      const bool v = (rr >= 0) && (rr < 64) && (cc >= 0) && (cc < 64);
      const int j = v ? (rr * 64 + cc) : wid;
      const float* tj = T + (size_t)j * 512;
      float s = 0.f;
#pragma unroll
      for (int u = 0; u < 8; u++) s = fmaf(hreg[u], tj[u * 64 + lane], s);
#pragma unroll
      for (int off = 32; off > 0; off >>= 1) s += __shfl_xor(s, off, 64);
      sv[q] = v ? s : -3.4e38f;
      jv[q] = j;
      ok[q] = v;
      q++;
    }

  float m = sv[0];
#pragma unroll
  for (int i = 1; i < 8; i++) m = fmaxf(m, sv[i]);
  float e[8], den = 0.f;
#pragma unroll
  for (int i = 0; i < 8; i++) {
    e[i] = ok[i] ? expf(sv[i] - m) : 0.f;
    den += e[i];
  }
  const float inv = 1.f / den;

  float outv[8];
#pragma unroll
  for (int u = 0; u < 8; u++) outv[u] = 0.f;
#pragma unroll
  for (int i = 0; i < 8; i++) {
    const float al = e[i] * inv;
    const float* hj = H2 + (size_t)jv[i] * 1024;
#pragma unroll
    for (int u = 0; u < 8; u++) outv[u] = fmaf(al, hj[u * 64 + lane], outv[u]);
  }
  float* dst = H2 + (size_t)wid * 1024 + 512;
#pragma unroll
  for (int u = 0; u < 8; u++) dst[u * 64 + lane] = outv[u];
}

// ---------------------------------------------------------------------------
// tl[t,n] = P[n,:] . templates[t,:]   (one wave per instance)
// ---------------------------------------------------------------------------
__launch_bounds__(256)
__global__ void templ_scores(const float* __restrict__ P, const float* __restrict__ tmpl,
                             float* __restrict__ tl) {
  const int wid = (blockIdx.x * 256 + threadIdx.x) >> 6;
  const int lane = threadIdx.x & 63;
  const float* p = P + (size_t)wid * 1024;
  float pr[16];
#pragma unroll
  for (int u = 0; u < 16; u++) pr[u] = p[u * 64 + lane];
  for (int t = 0; t < 10; t++) {
    const float* tp = tmpl + t * 1024;
    float s = 0.f;
#pragma unroll
    for (int u = 0; u < 16; u++) s = fmaf(pr[u], tp[u * 64 + lane], s);
#pragma unroll
    for (int off = 32; off > 0; off >>= 1) s += __shfl_xor(s, off, 64);
    if (lane == 0) tl[t * NINST + wid] = s;
  }
}

// ---------------------------------------------------------------------------
// Per-template softmax over N=4096 (one block per template)
// ---------------------------------------------------------------------------
__launch_bounds__(256)
__global__ void softmax_rows(const float* __restrict__ tl, float* __restrict__ betas) {
  const int t = blockIdx.x, tid = threadIdx.x;
  __shared__ float red[256];
  const float* row = tl + t * NINST;
  float m = -3.4e38f;
  for (int i = tid; i < NINST; i += 256) m = fmaxf(m, row[i]);
  red[tid] = m;
  __syncthreads();
  for (int s = 128; s > 0; s >>= 1) {
    if (tid < s) red[tid] = fmaxf(red[tid], red[tid + s]);
    __syncthreads();
  }
  m = red[0];
  __syncthreads();
  float sum = 0.f;
  for (int i = tid; i < NINST; i += 256) sum += expf(row[i] - m);
  red[tid] = sum;
  __syncthreads();
  for (int s = 128; s > 0; s >>= 1) {
    if (tid < s) red[tid] += red[tid + s];
    __syncthreads();
  }
  const float inv = 1.f / red[0];
  for (int i = tid; i < NINST; i += 256) betas[t * NINST + i] = expf(row[i] - m) * inv;
}

// ---------------------------------------------------------------------------
// embs[t,k] = sum_n betas[t,n] * H2[n,k]    grid (4 k-chunks, 10 templates)
// ---------------------------------------------------------------------------
__launch_bounds__(256)
__global__ void embs_k(const float* __restrict__ betas, const float* __restrict__ H2,
                       float* __restrict__ embs) {
  const int t = blockIdx.y;
  const int k = blockIdx.x * 256 + threadIdx.x;
  const float* br = betas + t * NINST;
  float a = 0.f;
  for (int n = 0; n < NINST; n++) a = fmaf(br[n], H2[(size_t)n * 1024 + k], a);
  embs[t * 1024 + k] = a;
}

// ---------------------------------------------------------------------------
// Global attention tail: g, gammas, M, Y_prob, Y_hat. Single block.
// ---------------------------------------------------------------------------
__launch_bounds__(256)
__global__ void ga_k(const float* __restrict__ embs_g, const float* __restrict__ ga1_w,
                     const float* __restrict__ ga1_b, const float* __restrict__ ga2_w,
                     const float* __restrict__ ga2_b, const float* __restrict__ cls_w,
                     const float* __restrict__ cls_b, float* __restrict__ out,
                     float* __restrict__ gammas_ws) {
  __shared__ __align__(16) float embs_s[10 * 1024];
  __shared__ float hh[10 * 128];
  __shared__ float red[256];
  __shared__ float g_s[10], gam_s[10];
  __shared__ float M_s[1024];
  const int tid = threadIdx.x;
  const int wave = tid >> 6, lane = tid & 63;

  for (int i = tid; i < 10240; i += 256) embs_s[i] = embs_g[i];
  __syncthreads();

  for (int j = 0; j < 32; j++) {
    const int d = wave * 32 + j;
    float wreg[16];
#pragma unroll
    for (int u = 0; u < 16; u++) wreg[u] = ga1_w[(size_t)d * 1024 + u * 64 + lane];
    const float bd = ga1_b[d];
    for (int t = 0; t < 10; t++) {
      float s = 0.f;
#pragma unroll
      for (int u = 0; u < 16; u++) s = fmaf(wreg[u], embs_s[t * 1024 + u * 64 + lane], s);
#pragma unroll
      for (int off = 32; off > 0; off >>= 1) s += __shfl_xor(s, off, 64);
      if (lane == 0) hh[t * 128 + d] = tanhf(s + bd);
    }
  }
  __syncthreads();

  if (wave == 0) {
    for (int t = 0; t < 10; t++) {
      float s = hh[t * 128 + lane] * ga2_w[lane] + hh[t * 128 + 64 + lane] * ga2_w[64 + lane];
#pragma unroll
      for (int off = 32; off > 0; off >>= 1) s += __shfl_xor(s, off, 64);
      if (lane == 0) g_s[t] = s + ga2_b[0];
    }
  }
  __syncthreads();

  if (tid == 0) {
    float m = g_s[0];
    for (int t = 1; t < 10; t++) m = fmaxf(m, g_s[t]);
    float sum = 0.f;
    for (int t = 0; t < 10; t++) sum += expf(g_s[t] - m);
    for (int t = 0; t < 10; t++) {
      gam_s[t] = expf(g_s[t] - m) / sum;
      gammas_ws[t] = gam_s[t];
    }
  }
  __syncthreads();

  for (int k = tid; k < 1024; k += 256) {
    float a = 0.f;
#pragma unroll
    for (int t = 0; t < 10; t++) a = fmaf(gam_s[t], embs_s[t * 1024 + k], a);
    M_s[k] = a;
  }
  __syncthreads();

  float part = 0.f;
  for (int k = tid; k < 1024; k += 256) part = fmaf(M_s[k], cls_w[k], part);
  red[tid] = part;
  __syncthreads();
  for (int s = 128; s > 0; s >>= 1) {
    if (tid < s) red[tid] += red[tid + s];
    __syncthreads();
  }
  if (tid == 0) {
    const float z = red[0] + cls_b[0];
    const float yp = 1.f / (1.f + expf(-z));
    out[0] = yp;
    out[1] = (yp >= 0.5f) ? 1.f : 0.f;
  }
}

// ---------------------------------------------------------------------------
// A[n] = sum_t gammas[t] * betas[t,n]
// ---------------------------------------------------------------------------
__launch_bounds__(256)
__global__ void a_k(const float* __restrict__ betas, const float* __restrict__ gam,
                    float* __restrict__ outA) {
  const int n = blockIdx.x * 256 + threadIdx.x;
  float a = 0.f;
#pragma unroll
  for (int t = 0; t < 10; t++) a = fmaf(gam[t], betas[t * NINST + n], a);
  outA[n] = a;
}

// ---------------------------------------------------------------------------
extern "C" void kernel_launch(void* const* d_in, const int* in_sizes, int n_in,
                              void* d_out, int out_size, void* d_ws, size_t ws_size,
                              hipStream_t stream) {
  const float* x       = (const float*)d_in[0];
  const float* w1      = (const float*)d_in[2];
  const float* b1      = (const float*)d_in[3];
  const float* w2      = (const float*)d_in[4];
  const float* b2      = (const float*)d_in[5];
  const float* fc1_w   = (const float*)d_in[6];
  const float* fc1_b   = (const float*)d_in[7];
  const float* fc2_w   = (const float*)d_in[8];
  const float* fc2_b   = (const float*)d_in[9];
  const float* nbr_w   = (const float*)d_in[10];
  const float* nbr_b   = (const float*)d_in[11];
  const float* tmpl    = (const float*)d_in[12];
  const float* proto_w = (const float*)d_in[13];
  const float* proto_b = (const float*)d_in[14];
  const float* ga1_w   = (const float*)d_in[15];
  const float* ga1_b   = (const float*)d_in[16];
  const float* ga2_w   = (const float*)d_in[17];
  const float* ga2_b   = (const float*)d_in[18];
  const float* cls_w   = (const float*)d_in[19];
  const float* cls_b   = (const float*)d_in[20];
  float* out = (float*)d_out;

  float* ws   = (float*)d_ws;
  float* emb  = ws;                      // 4096*1728
  float* H2   = emb + 4096 * 1728;       // 4096*1024 (cols 0..511 = H, 512.. = nbhd)
  float* H1   = H2 + 4096 * 1024;        // 4096*512
  float* Tb   = H1 + 4096 * 512;         // 4096*512
  float* P    = Tb + 4096 * 512;         // 4096*1024
  float* tl   = P + 4096 * 1024;         // 10*4096
  float* bet  = tl + 10 * NINST;         // 10*4096
  float* embs = bet + 10 * NINST;        // 10*1024
  float* gam  = embs + 10 * 1024;        // 10

  conv_fused<<<NINST, 256, 0, stream>>>(x, w1, b1, w2, b2, emb);
  gemm_bt<1><<<dim3(8, 64), 256, 0, stream>>>(emb, fc1_w, fc1_b, H1, 1728, 1728, 1728, 512);
  gemm_bt<1><<<dim3(8, 64), 256, 0, stream>>>(H1, fc2_w, fc2_b, H2, 512, 512, 512, 1024);
  gemm_bt<2><<<dim3(8, 64), 256, 0, stream>>>(H2, nbr_w, nbr_b, Tb, 512, 1024, 512, 512);
  nbhd_k<<<1024, 256, 0, stream>>>(H2, Tb);
  gemm_bt<2><<<dim3(16, 64), 256, 0, stream>>>(H2, proto_w, proto_b, P, 1024, 1024, 1024, 1024);
  templ_scores<<<1024, 256, 0, stream>>>(P, tmpl, tl);
  softmax_rows<<<10, 256, 0, stream>>>(tl, bet);
  embs_k<<<dim3(4, 10), 256, 0, stream>>>(bet, H2, embs);
  ga_k<<<1, 256, 0, stream>>>(embs, ga1_w, ga1_b, ga2_w, ga2_b, cls_w, cls_b, out, gam);
  a_k<<<16, 256, 0, stream>>>(bet, gam, out + 2);
}

// Round 4
// 942.174 us; speedup vs baseline: 5.3634x; 1.2822x over previous
//
#include <hip/hip_runtime.h>
#include <math.h>

#define NINST 4096

typedef _Float16 half8 __attribute__((ext_vector_type(8)));
typedef float floatx4 __attribute__((ext_vector_type(4)));
typedef float floatx2 __attribute__((ext_vector_type(2)));

// ---------------------------------------------------------------------------
// Fused conv1(4x4)+relu+pool2 + conv2(3x3)+relu+pool2, one block per instance.
// x:(N,3,32,32) -> emb fp16:(N,1728)   [flatten order oc*36 + py*6 + px]
// x loads are non-temporal so w1/w2 stay resident in per-XCD L2.
// ---------------------------------------------------------------------------
__launch_bounds__(256, 3)
__global__ void conv_fused(const float* __restrict__ x,
                           const float* __restrict__ w1, const float* __restrict__ b1,
                           const float* __restrict__ w2, const float* __restrict__ b2,
                           _Float16* __restrict__ emb) {
  __shared__ __align__(16) float smem[12816];
  float* xw  = smem;          // x overlay w2-chunk
  float* w1s = smem + 3888;
  float* h1  = smem + 5688;

  const int n = blockIdx.x;
  const int tid = threadIdx.x;

  // ---- stage x (rows padded to 34, non-temporal) and w1 (oc stride 50) ----
  {
    const floatx2* xg = (const floatx2*)(x + (size_t)n * 3072);
    for (int i = tid; i < 1536; i += 256) {
      const int f = i * 2;
      const int ic = f >> 10, rem = f & 1023, yy = rem >> 5, xx = rem & 31;
      floatx2 v = __builtin_nontemporal_load(&xg[i]);
      *(floatx2*)&xw[ic * 1088 + yy * 34 + xx] = v;
    }
    for (int i = tid; i < 1728; i += 256) {
      const int oc = i / 48, r = i - oc * 48;
      w1s[oc * 50 + r] = w1[i];
    }
  }
  __syncthreads();

  // ---- conv1 + relu + pool -> h1 ----
  if (tid < 252) {
    const int oc = tid / 7, rp = tid % 7;
    const float bia = b1[oc];
#pragma unroll
    for (int rp2 = 0; rp2 < 2; rp2++) {
      const int pr = 2 * rp + rp2;
      float pm[14];
#pragma unroll
      for (int upy = 0; upy < 2; upy++) {
        const int y = 2 * pr + upy;
#pragma unroll
        for (int half = 0; half < 2; half++) {
          const int cb = half * 14;
          float ra[14];
#pragma unroll
          for (int c = 0; c < 14; c++) ra[c] = 0.f;
#pragma unroll
          for (int ic = 0; ic < 3; ic++) {
            float wv[16];
            {
              const float2* wp = (const float2*)&w1s[oc * 50 + ic * 16];
#pragma unroll
              for (int j = 0; j < 8; j++) {
                float2 t = wp[j];
                wv[2 * j] = t.x; wv[2 * j + 1] = t.y;
              }
            }
#pragma unroll
            for (int ky = 0; ky < 4; ky++) {
              float xr[18];
              const float2* rowp = (const float2*)&xw[ic * 1088 + (y + ky) * 34 + cb];
#pragma unroll
              for (int j = 0; j < 9; j++) {
                float2 t = rowp[j];
                xr[2 * j] = t.x; xr[2 * j + 1] = t.y;
              }
#pragma unroll
              for (int kx = 0; kx < 4; kx++) {
                const float w = wv[ky * 4 + kx];
#pragma unroll
                for (int c = 0; c < 14; c++) ra[c] = fmaf(w, xr[c + kx], ra[c]);
              }
            }
          }
#pragma unroll
          for (int c = 0; c < 7; c++) {
            const float v = fmaxf(ra[2 * c], ra[2 * c + 1]);
            const int pc = half * 7 + c;
            if (upy == 0) pm[pc] = v; else pm[pc] = fmaxf(pm[pc], v);
          }
        }
      }
#pragma unroll
      for (int c = 0; c < 7; c++) {
        float2 o;
        o.x = fmaxf(pm[2 * c] + bia, 0.f);
        o.y = fmaxf(pm[2 * c + 1] + bia, 0.f);
        *(float2*)&h1[oc * 198 + pr * 14 + 2 * c] = o;
      }
    }
  }

  // ---- conv2 + relu + pool ----
  const int ty = tid >> 4, tx = tid & 15;
  const bool act2 = (tx < 12);
  float acc[3][12];
#pragma unroll
  for (int j = 0; j < 3; j++)
#pragma unroll
    for (int q = 0; q < 12; q++) acc[j][q] = 0.f;

  for (int c = 0; c < 4; c++) {
    __syncthreads();
    for (int i = tid; i < 3888; i += 256) {
      const int oc = i / 81, r = i - oc * 81;
      xw[i] = w2[oc * 324 + c * 81 + r];
    }
    __syncthreads();
    if (act2) {
#pragma unroll
      for (int icl = 0; icl < 9; icl++) {
        const int ic = c * 9 + icl;
        float wr[3][9];
#pragma unroll
        for (int j = 0; j < 3; j++)
#pragma unroll
          for (int t = 0; t < 9; t++)
            wr[j][t] = xw[(ty * 3 + j) * 81 + icl * 9 + t];
#pragma unroll
        for (int ky = 0; ky < 3; ky++) {
          float xr[14];
          const float2* rowp = (const float2*)&h1[ic * 198 + (tx + ky) * 14];
#pragma unroll
          for (int j = 0; j < 7; j++) {
            float2 t = rowp[j];
            xr[2 * j] = t.x; xr[2 * j + 1] = t.y;
          }
#pragma unroll
          for (int kx = 0; kx < 3; kx++)
#pragma unroll
            for (int j = 0; j < 3; j++) {
              const float w = wr[j][ky * 3 + kx];
#pragma unroll
              for (int q = 0; q < 12; q++)
                acc[j][q] = fmaf(w, xr[q + kx], acc[j][q]);
            }
        }
      }
    }
  }

  __syncthreads();   // all h1 reads done; reuse h1 region as emb staging
  if (act2) {
#pragma unroll
    for (int j = 0; j < 3; j++) {
      const int oc = ty * 3 + j;
      const float bia = b2[oc];
#pragma unroll
      for (int q = 0; q < 6; q++) {
        const float m = fmaxf(acc[j][2 * q], acc[j][2 * q + 1]);
        const float o = __shfl_xor(m, 1, 64);
        if ((tx & 1) == 0) {
          h1[oc * 36 + (tx >> 1) * 6 + q] = fmaxf(fmaxf(m, o) + bia, 0.f);
        }
      }
    }
  }
  __syncthreads();
  {
    _Float16* dst = emb + (size_t)n * 1728;
    for (int i = tid; i < 1728; i += 256) dst[i] = (_Float16)h1[i];
  }
}

// ---------------------------------------------------------------------------
// fp32 -> fp16 cast (n multiple of 4)
// ---------------------------------------------------------------------------
__global__ void cast_f2h(const float* __restrict__ src, _Float16* __restrict__ dst, int n) {
  const int i = (blockIdx.x * 256 + threadIdx.x) * 4;
  if (i < n) {
    const float4 v = *(const float4*)(src + i);
    _Float16 o0 = (_Float16)v.x, o1 = (_Float16)v.y, o2 = (_Float16)v.z, o3 = (_Float16)v.w;
    ushort4 pk;
    pk.x = __builtin_bit_cast(unsigned short, o0);
    pk.y = __builtin_bit_cast(unsigned short, o1);
    pk.z = __builtin_bit_cast(unsigned short, o2);
    pk.w = __builtin_bit_cast(unsigned short, o3);
    *(ushort4*)(dst + i) = pk;
  }
}

// ---------------------------------------------------------------------------
// fp16 MFMA GEMM: C[m,n] = act( sum_k A[m,k]*B[n,k] + bias[n] )
// BM=128, BN=64, BK=64, 256 threads (4 waves), wave tile 64x32 (4x2 MFMA tiles)
// LDS rows padded to 72 halves (144 B).
// ACT: 0=none 1=relu 2=tanh.  M%128==0, N%64==0, K%64==0 (true for all calls).
// ---------------------------------------------------------------------------
template <int ACT>
__launch_bounds__(256)
__global__ void gemm_h(const _Float16* __restrict__ A, const _Float16* __restrict__ B,
                       const float* __restrict__ bias, _Float16* __restrict__ C,
                       int K, int lda, int ldb, int ldc) {
  __shared__ __align__(16) _Float16 As[128 * 72];
  __shared__ __align__(16) _Float16 Bs[64 * 72];
  const int tid = threadIdx.x;
  const int m0 = blockIdx.y * 128, n0 = blockIdx.x * 64;
  const int lane = tid & 63, wave = tid >> 6;
  const int quad = lane >> 4, l15 = lane & 15;
  const int wm = (wave >> 1) * 64, wn = (wave & 1) * 32;
  const int arow = tid >> 3, acol = (tid & 7) * 8;   // staging: 32 rows x 8 chunks

  floatx4 acc[4][2];
#pragma unroll
  for (int i = 0; i < 4; i++)
#pragma unroll
    for (int j = 0; j < 2; j++)
#pragma unroll
      for (int r = 0; r < 4; r++) acc[i][j][r] = 0.f;

  for (int k0 = 0; k0 < K; k0 += 64) {
    half8 av[4], bv[2];
#pragma unroll
    for (int i = 0; i < 4; i++)
      av[i] = *(const half8*)&A[(size_t)(m0 + arow + 32 * i) * lda + k0 + acol];
#pragma unroll
    for (int i = 0; i < 2; i++)
      bv[i] = *(const half8*)&B[(size_t)(n0 + arow + 32 * i) * ldb + k0 + acol];
    __syncthreads();   // previous iteration's LDS reads done
#pragma unroll
    for (int i = 0; i < 4; i++) *(half8*)&As[(arow + 32 * i) * 72 + acol] = av[i];
#pragma unroll
    for (int i = 0; i < 2; i++) *(half8*)&Bs[(arow + 32 * i) * 72 + acol] = bv[i];
    __syncthreads();
#pragma unroll
    for (int ks = 0; ks < 64; ks += 32) {
      half8 af[4], bf[2];
#pragma unroll
      for (int mt = 0; mt < 4; mt++)
        af[mt] = *(const half8*)&As[(wm + mt * 16 + l15) * 72 + ks + quad * 8];
#pragma unroll
      for (int nt = 0; nt < 2; nt++)
        bf[nt] = *(const half8*)&Bs[(wn + nt * 16 + l15) * 72 + ks + quad * 8];
#pragma unroll
      for (int mt = 0; mt < 4; mt++)
#pragma unroll
        for (int nt = 0; nt < 2; nt++)
          acc[mt][nt] = __builtin_amdgcn_mfma_f32_16x16x32_f16(af[mt], bf[nt], acc[mt][nt], 0, 0, 0);
    }
  }

#pragma unroll
  for (int nt = 0; nt < 2; nt++) {
    const int col = n0 + wn + nt * 16 + l15;
    const float bcol = bias[col];
#pragma unroll
    for (int mt = 0; mt < 4; mt++) {
#pragma unroll
      for (int r = 0; r < 4; r++) {
        const int row = m0 + wm + mt * 16 + quad * 4 + r;
        float v = acc[mt][nt][r] + bcol;
        if (ACT == 1) v = fmaxf(v, 0.f);
        if (ACT == 2) v = tanhf(v);
        C[(size_t)row * ldc + col] = (_Float16)v;
      }
    }
  }
}

// ---------------------------------------------------------------------------
// Neighborhood attention: one wave per instance. <=8 grid neighbors.
// H lives in H2h[:, :512] (fp16); writes nbhd into H2h[:, 512:1024] (fp16).
// ---------------------------------------------------------------------------
__launch_bounds__(256)
__global__ void nbhd_k(_Float16* __restrict__ H2, const _Float16* __restrict__ T) {
  const int wid = (blockIdx.x * 256 + threadIdx.x) >> 6;   // instance
  const int lane = threadIdx.x & 63;
  const int r = wid >> 6, c = wid & 63;
  const _Float16* hi = H2 + (size_t)wid * 1024;
  float hreg[8];
#pragma unroll
  for (int u = 0; u < 8; u++) hreg[u] = (float)hi[u * 64 + lane];

  float sv[8];
  int jv[8];
  bool ok[8];
  int q = 0;
#pragma unroll
  for (int dr = -1; dr <= 1; dr++)
#pragma unroll
    for (int dc = -1; dc <= 1; dc++) {
      if (dr == 0 && dc == 0) continue;
      const int rr = r + dr, cc = c + dc;
      const bool v = (rr >= 0) && (rr < 64) && (cc >= 0) && (cc < 64);
      const int j = v ? (rr * 64 + cc) : wid;
      const _Float16* tj = T + (size_t)j * 512;
      float s = 0.f;
#pragma unroll
      for (int u = 0; u < 8; u++) s = fmaf(hreg[u], (float)tj[u * 64 + lane], s);
#pragma unroll
      for (int off = 32; off > 0; off >>= 1) s += __shfl_xor(s, off, 64);
      sv[q] = v ? s : -3.4e38f;
      jv[q] = j;
      ok[q] = v;
      q++;
    }

  float m = sv[0];
#pragma unroll
  for (int i = 1; i < 8; i++) m = fmaxf(m, sv[i]);
  float e[8], den = 0.f;
#pragma unroll
  for (int i = 0; i < 8; i++) {
    e[i] = ok[i] ? expf(sv[i] - m) : 0.f;
    den += e[i];
  }
  const float inv = 1.f / den;

  float outv[8];
#pragma unroll
  for (int u = 0; u < 8; u++) outv[u] = 0.f;
#pragma unroll
  for (int i = 0; i < 8; i++) {
    const float al = e[i] * inv;
    const _Float16* hj = H2 + (size_t)jv[i] * 1024;
#pragma unroll
    for (int u = 0; u < 8; u++) outv[u] = fmaf(al, (float)hj[u * 64 + lane], outv[u]);
  }
  _Float16* dst = H2 + (size_t)wid * 1024 + 512;
#pragma unroll
  for (int u = 0; u < 8; u++) dst[u * 64 + lane] = (_Float16)outv[u];
}

// ---------------------------------------------------------------------------
// tl[t,n] = P[n,:] . templates[t,:]   (one wave per instance, P fp16)
// ---------------------------------------------------------------------------
__launch_bounds__(256)
__global__ void templ_scores(const _Float16* __restrict__ P, const float* __restrict__ tmpl,
                             float* __restrict__ tl) {
  const int wid = (blockIdx.x * 256 + threadIdx.x) >> 6;
  const int lane = threadIdx.x & 63;
  const _Float16* p = P + (size_t)wid * 1024;
  float pr[16];
#pragma unroll
  for (int u = 0; u < 16; u++) pr[u] = (float)p[u * 64 + lane];
  for (int t = 0; t < 10; t++) {
    const float* tp = tmpl + t * 1024;
    float s = 0.f;
#pragma unroll
    for (int u = 0; u < 16; u++) s = fmaf(pr[u], tp[u * 64 + lane], s);
#pragma unroll
    for (int off = 32; off > 0; off >>= 1) s += __shfl_xor(s, off, 64);
    if (lane == 0) tl[t * NINST + wid] = s;
  }
}

// ---------------------------------------------------------------------------
// Per-template softmax over N=4096 (one block per template)
// ---------------------------------------------------------------------------
__launch_bounds__(256)
__global__ void softmax_rows(const float* __restrict__ tl, float* __restrict__ betas) {
  const int t = blockIdx.x, tid = threadIdx.x;
  __shared__ float red[256];
  const float* row = tl + t * NINST;
  float m = -3.4e38f;
  for (int i = tid; i < NINST; i += 256) m = fmaxf(m, row[i]);
  red[tid] = m;
  __syncthreads();
  for (int s = 128; s > 0; s >>= 1) {
    if (tid < s) red[tid] = fmaxf(red[tid], red[tid + s]);
    __syncthreads();
  }
  m = red[0];
  __syncthreads();
  float sum = 0.f;
  for (int i = tid; i < NINST; i += 256) sum += expf(row[i] - m);
  red[tid] = sum;
  __syncthreads();
  for (int s = 128; s > 0; s >>= 1) {
    if (tid < s) red[tid] += red[tid + s];
    __syncthreads();
  }
  const float inv = 1.f / red[0];
  for (int i = tid; i < NINST; i += 256) betas[t * NINST + i] = expf(row[i] - m) * inv;
}

__global__ void zero_embs(float* __restrict__ embs) {
  for (int i = threadIdx.x; i < 10 * 1024; i += 256) embs[i] = 0.f;
}

// ---------------------------------------------------------------------------
// embs[t,k] += sum_{n in slice} betas[t,n] * H2h[n,k]   grid (4 kc, 16 ns)
// ---------------------------------------------------------------------------
__launch_bounds__(256)
__global__ void embs_k(const float* __restrict__ betas, const _Float16* __restrict__ H2,
                       float* __restrict__ embs) {
  const int k = blockIdx.x * 256 + threadIdx.x;
  const int nbase = blockIdx.y * 256;
  float acc[10];
#pragma unroll
  for (int t = 0; t < 10; t++) acc[t] = 0.f;
  for (int n = nbase; n < nbase + 256; n++) {
    const float v = (float)H2[(size_t)n * 1024 + k];
#pragma unroll
    for (int t = 0; t < 10; t++) acc[t] = fmaf(betas[t * NINST + n], v, acc[t]);
  }
#pragma unroll
  for (int t = 0; t < 10; t++) atomicAdd(&embs[t * 1024 + k], acc[t]);
}

// ---------------------------------------------------------------------------
// Global attention tail: g, gammas, M, Y_prob, Y_hat. Single block.
// ---------------------------------------------------------------------------
__launch_bounds__(256)
__global__ void ga_k(const float* __restrict__ embs_g, const float* __restrict__ ga1_w,
                     const float* __restrict__ ga1_b, const float* __restrict__ ga2_w,
                     const float* __restrict__ ga2_b, const float* __restrict__ cls_w,
                     const float* __restrict__ cls_b, float* __restrict__ out,
                     float* __restrict__ gammas_ws) {
  __shared__ __align__(16) float embs_s[10 * 1024];
  __shared__ float hh[10 * 128];
  __shared__ float red[256];
  __shared__ float g_s[10], gam_s[10];
  __shared__ float M_s[1024];
  const int tid = threadIdx.x;
  const int wave = tid >> 6, lane = tid & 63;

  for (int i = tid; i < 10240; i += 256) embs_s[i] = embs_g[i];
  __syncthreads();

  for (int j = 0; j < 32; j++) {
    const int d = wave * 32 + j;
    float wreg[16];
#pragma unroll
    for (int u = 0; u < 16; u++) wreg[u] = ga1_w[(size_t)d * 1024 + u * 64 + lane];
    const float bd = ga1_b[d];
    for (int t = 0; t < 10; t++) {
      float s = 0.f;
#pragma unroll
      for (int u = 0; u < 16; u++) s = fmaf(wreg[u], embs_s[t * 1024 + u * 64 + lane], s);
#pragma unroll
      for (int off = 32; off > 0; off >>= 1) s += __shfl_xor(s, off, 64);
      if (lane == 0) hh[t * 128 + d] = tanhf(s + bd);
    }
  }
  __syncthreads();

  if (wave == 0) {
    for (int t = 0; t < 10; t++) {
      float s = hh[t * 128 + lane] * ga2_w[lane] + hh[t * 128 + 64 + lane] * ga2_w[64 + lane];
#pragma unroll
      for (int off = 32; off > 0; off >>= 1) s += __shfl_xor(s, off, 64);
      if (lane == 0) g_s[t] = s + ga2_b[0];
    }
  }
  __syncthreads();

  if (tid == 0) {
    float m = g_s[0];
    for (int t = 1; t < 10; t++) m = fmaxf(m, g_s[t]);
    float sum = 0.f;
    for (int t = 0; t < 10; t++) sum += expf(g_s[t] - m);
    for (int t = 0; t < 10; t++) {
      gam_s[t] = expf(g_s[t] - m) / sum;
      gammas_ws[t] = gam_s[t];
    }
  }
  __syncthreads();

  for (int k = tid; k < 1024; k += 256) {
    float a = 0.f;
#pragma unroll
    for (int t = 0; t < 10; t++) a = fmaf(gam_s[t], embs_s[t * 1024 + k], a);
    M_s[k] = a;
  }
  __syncthreads();

  float part = 0.f;
  for (int k = tid; k < 1024; k += 256) part = fmaf(M_s[k], cls_w[k], part);
  red[tid] = part;
  __syncthreads();
  for (int s = 128; s > 0; s >>= 1) {
    if (tid < s) red[tid] += red[tid + s];
    __syncthreads();
  }
  if (tid == 0) {
    const float z = red[0] + cls_b[0];
    const float yp = 1.f / (1.f + expf(-z));
    out[0] = yp;
    out[1] = (yp >= 0.5f) ? 1.f : 0.f;
  }
}

// ---------------------------------------------------------------------------
// A[n] = sum_t gammas[t] * betas[t,n]
// ---------------------------------------------------------------------------
__launch_bounds__(256)
__global__ void a_k(const float* __restrict__ betas, const float* __restrict__ gam,
                    float* __restrict__ outA) {
  const int n = blockIdx.x * 256 + threadIdx.x;
  float a = 0.f;
#pragma unroll
  for (int t = 0; t < 10; t++) a = fmaf(gam[t], betas[t * NINST + n], a);
  outA[n] = a;
}

// ---------------------------------------------------------------------------
extern "C" void kernel_launch(void* const* d_in, const int* in_sizes, int n_in,
                              void* d_out, int out_size, void* d_ws, size_t ws_size,
                              hipStream_t stream) {
  const float* x       = (const float*)d_in[0];
  const float* w1      = (const float*)d_in[2];
  const float* b1      = (const float*)d_in[3];
  const float* w2      = (const float*)d_in[4];
  const float* b2      = (const float*)d_in[5];
  const float* fc1_w   = (const float*)d_in[6];
  const float* fc1_b   = (const float*)d_in[7];
  const float* fc2_w   = (const float*)d_in[8];
  const float* fc2_b   = (const float*)d_in[9];
  const float* nbr_w   = (const float*)d_in[10];
  const float* nbr_b   = (const float*)d_in[11];
  const float* tmpl    = (const float*)d_in[12];
  const float* proto_w = (const float*)d_in[13];
  const float* proto_b = (const float*)d_in[14];
  const float* ga1_w   = (const float*)d_in[15];
  const float* ga1_b   = (const float*)d_in[16];
  const float* ga2_w   = (const float*)d_in[17];
  const float* ga2_b   = (const float*)d_in[18];
  const float* cls_w   = (const float*)d_in[19];
  const float* cls_b   = (const float*)d_in[20];
  float* out = (float*)d_out;

  char* w = (char*)d_ws;
  _Float16* embh   = (_Float16*)w;  w += (size_t)4096 * 1728 * 2;
  _Float16* H1h    = (_Float16*)w;  w += (size_t)4096 * 512 * 2;
  _Float16* H2h    = (_Float16*)w;  w += (size_t)4096 * 1024 * 2;
  _Float16* TbH    = (_Float16*)w;  w += (size_t)4096 * 512 * 2;
  _Float16* PH     = (_Float16*)w;  w += (size_t)4096 * 1024 * 2;
  _Float16* fc1wH  = (_Float16*)w;  w += (size_t)512 * 1728 * 2;
  _Float16* fc2wH  = (_Float16*)w;  w += (size_t)512 * 512 * 2;
  _Float16* nbrwH  = (_Float16*)w;  w += (size_t)512 * 512 * 2;
  _Float16* protowH= (_Float16*)w;  w += (size_t)1024 * 1024 * 2;
  float* tl   = (float*)w;          w += (size_t)10 * NINST * 4;
  float* bet  = (float*)w;          w += (size_t)10 * NINST * 4;
  float* embs = (float*)w;          w += (size_t)10 * 1024 * 4;
  float* gam  = (float*)w;          w += 256;

  // weight casts (independent of conv)
  cast_f2h<<<(512 * 1728 / 4 + 255) / 256, 256, 0, stream>>>(fc1_w, fc1wH, 512 * 1728);
  cast_f2h<<<(512 * 512 / 4 + 255) / 256, 256, 0, stream>>>(fc2_w, fc2wH, 512 * 512);
  cast_f2h<<<(512 * 512 / 4 + 255) / 256, 256, 0, stream>>>(nbr_w, nbrwH, 512 * 512);
  cast_f2h<<<(1024 * 1024 / 4 + 255) / 256, 256, 0, stream>>>(proto_w, protowH, 1024 * 1024);

  conv_fused<<<NINST, 256, 0, stream>>>(x, w1, b1, w2, b2, embh);

  // fc1: (4096x1728)x(512x1728)^T -> H1h relu
  gemm_h<1><<<dim3(8, 32), 256, 0, stream>>>(embh, fc1wH, fc1_b, H1h, 1728, 1728, 1728, 512);
  // fc2: (4096x512)x(512x512)^T -> H2h[:, :512] relu
  gemm_h<1><<<dim3(8, 32), 256, 0, stream>>>(H1h, fc2wH, fc2_b, H2h, 512, 512, 512, 1024);
  // nbr: tanh((4096x512)x(512x512)^T) -> TbH
  gemm_h<2><<<dim3(8, 32), 256, 0, stream>>>(H2h, nbrwH, nbr_b, TbH, 512, 1024, 512, 512);
  nbhd_k<<<1024, 256, 0, stream>>>(H2h, TbH);
  // proto: tanh((4096x1024)x(1024x1024)^T) -> PH
  gemm_h<2><<<dim3(16, 32), 256, 0, stream>>>(H2h, protowH, proto_b, PH, 1024, 1024, 1024, 1024);
  templ_scores<<<1024, 256, 0, stream>>>(PH, tmpl, tl);
  softmax_rows<<<10, 256, 0, stream>>>(tl, bet);
  zero_embs<<<1, 256, 0, stream>>>(embs);
  embs_k<<<dim3(4, 16), 256, 0, stream>>>(bet, H2h, embs);
  ga_k<<<1, 256, 0, stream>>>(embs, ga1_w, ga1_b, ga2_w, ga2_b, cls_w, cls_b, out, gam);
  a_k<<<16, 256, 0, stream>>>(bet, gam, out + 2);
}

// Round 5
// 618.232 us; speedup vs baseline: 8.1737x; 1.5240x over previous
//
#include <hip/hip_runtime.h>
#include <math.h>

#define NINST 4096

typedef _Float16 half8 __attribute__((ext_vector_type(8)));
typedef _Float16 half4 __attribute__((ext_vector_type(4)));
typedef float floatx4 __attribute__((ext_vector_type(4)));

// ---------------------------------------------------------------------------
// xform_x: x (N,3,32,32) fp32 -> xh (N,1024 pixels,4) fp16 channel-last, ic3=0
// ---------------------------------------------------------------------------
__global__ void xform_x(const float* __restrict__ x, _Float16* __restrict__ xh) {
  const int g = blockIdx.x * 256 + threadIdx.x;   // pixel id over 4096*1024
  const int n = g >> 10, p = g & 1023;
  const float* xb = x + (size_t)n * 3072;
  half4 v;
  v[0] = (_Float16)xb[p];
  v[1] = (_Float16)xb[1024 + p];
  v[2] = (_Float16)xb[2048 + p];
  v[3] = (_Float16)0.f;
  *(half4*)&xh[(size_t)g * 4] = v;
}

// ---------------------------------------------------------------------------
// xform_w1: w1 (36,3,4,4) -> w1t [48 oc][68] fp16, k = ky*16+kx*4+ic (k<64),
// zeros at ic==3, oc>=36, k>=64.
// ---------------------------------------------------------------------------
__global__ void xform_w1(const float* __restrict__ w1, _Float16* __restrict__ w1t) {
  for (int i = threadIdx.x; i < 48 * 68; i += 256) {
    const int oc = i / 68, k = i % 68;
    float v = 0.f;
    if (k < 64) {
      const int ky = k >> 4, r = k & 15, kx = r >> 2, ic = r & 3;
      if (oc < 36 && ic < 3) v = w1[((oc * 3 + ic) * 4 + ky) * 4 + kx];
    }
    w1t[i] = (_Float16)v;
  }
}

// ---------------------------------------------------------------------------
// xform_w2: w2 (48,36,3,3) -> w2t [3 ky][48 oc][132] fp16, k = kx*40+ic (k<120),
// zeros at ic>=36 and k>=120.
// ---------------------------------------------------------------------------
__global__ void xform_w2(const float* __restrict__ w2, _Float16* __restrict__ w2t) {
  for (int i = threadIdx.x; i < 3 * 48 * 132; i += 256) {
    const int ky = i / 6336, r = i % 6336;
    const int oc = r / 132, k = r % 132;
    float v = 0.f;
    if (k < 120) {
      const int kx = k / 40, ic = k % 40;
      if (ic < 36) v = w2[((oc * 36 + ic) * 3 + ky) * 3 + kx];
    }
    w2t[i] = (_Float16)v;
  }
}

// ---------------------------------------------------------------------------
// MFMA conv: conv1(4x4)+pool+relu -> h1 (LDS, channel-last [196][40]),
//            conv2(3x3)+pool+relu -> emb (N,1728). One block per instance.
// Pool-aligned m-mapping: m = window*4 + (dy*2+dx) so each C-quad's 4 regs
// form one 2x2 pool window (pooled in registers, relu(max+bias)).
// LDS 43.1 KB -> 3 blocks/CU.
// ---------------------------------------------------------------------------
__launch_bounds__(256, 3)
__global__ void conv_fused(const _Float16* __restrict__ xh,
                           const _Float16* __restrict__ w1t_g,
                           const _Float16* __restrict__ w2t_g,
                           const float* __restrict__ b1, const float* __restrict__ b2,
                           _Float16* __restrict__ emb) {
  __shared__ __align__(16) _Float16 smem[21552];
  _Float16* x_s   = smem;            // 4096 halves (overlay h2s 1728 later)
  _Float16* w1t_s = smem + 4096;     // 3264
  _Float16* h1_s  = smem + 7360;     // 7856 (196*40 + 16 zero pad)
  _Float16* w2t_s = smem + 15216;    // 6336

  const int n = blockIdx.x, tid = threadIdx.x;
  const int lane = tid & 63, wave = tid >> 6;
  const int quad = lane >> 4, l15 = lane & 15;

  // ---- stage x (channel-last fp16) and w1t ----
  {
    const half8* xg = (const half8*)(xh + (size_t)n * 4096);
    half8* xd = (half8*)x_s;
    for (int i = tid; i < 512; i += 256) xd[i] = xg[i];
    const half8* wg = (const half8*)w1t_g;
    half8* wd = (half8*)w1t_s;
    for (int i = tid; i < 408; i += 256) wd[i] = wg[i];
    if (tid < 16) h1_s[7840 + tid] = (_Float16)0.f;   // zero overrun pad
  }
  __syncthreads();

  // ---- conv1: M=784 (28x28 pre-pool), N=48 (36 real), K=64 (48 real) ----
  {
    half8 bc[2][3];
#pragma unroll
    for (int c = 0; c < 2; c++)
#pragma unroll
      for (int nt = 0; nt < 3; nt++)
        bc[c][nt] = *(const half8*)&w1t_s[(nt * 16 + l15) * 68 + c * 32 + quad * 8];
    float bia[3];
#pragma unroll
    for (int nt = 0; nt < 3; nt++) {
      const int oc = nt * 16 + l15;
      bia[nt] = (oc < 36) ? b1[oc] : 0.f;
    }
    for (int mt = wave; mt < 49; mt += 4) {
      const int mA = mt * 16 + l15;
      const int ppA = mA >> 2, dA = mA & 3;
      const int yA = 2 * (ppA / 14) + (dA >> 1);
      const int xA = 2 * (ppA % 14) + (dA & 1);
      floatx4 a1[3];
#pragma unroll
      for (int nt = 0; nt < 3; nt++)
#pragma unroll
        for (int r = 0; r < 4; r++) a1[nt][r] = 0.f;
#pragma unroll
      for (int c = 0; c < 2; c++) {
        const int row = yA + c * 2 + (quad >> 1);
        const half8 af = *(const half8*)&x_s[row * 128 + xA * 4 + (quad & 1) * 8];
#pragma unroll
        for (int nt = 0; nt < 3; nt++)
          a1[nt] = __builtin_amdgcn_mfma_f32_16x16x32_f16(af, bc[c][nt], a1[nt], 0, 0, 0);
      }
      const int ppC = mt * 4 + quad;
#pragma unroll
      for (int nt = 0; nt < 3; nt++) {
        const int oc = nt * 16 + l15;
        float v = fmaxf(fmaxf(a1[nt][0], a1[nt][1]), fmaxf(a1[nt][2], a1[nt][3])) + bia[nt];
        v = fmaxf(v, 0.f);
        if (oc < 40) h1_s[ppC * 40 + oc] = (_Float16)v;   // zeros land in ic-pad 36..39
      }
    }
  }

  // ---- conv2: M=144 (12x12 pre-pool), N=48, K=3ky x 128 (120 real) ----
  floatx4 acc2[3][3];
#pragma unroll
  for (int i = 0; i < 3; i++)
#pragma unroll
    for (int j = 0; j < 3; j++)
#pragma unroll
      for (int r = 0; r < 4; r++) acc2[i][j][r] = 0.f;

  for (int ky = 0; ky < 3; ky++) {
    __syncthreads();   // h1 ready (ky==0) / prev w2t chunk reads done
    {
      const half8* wg = (const half8*)(w2t_g + ky * 6336);
      half8* wd = (half8*)w2t_s;
      for (int i = tid; i < 792; i += 256) wd[i] = wg[i];
    }
    __syncthreads();
    half8 bc2[4][3];
#pragma unroll
    for (int c = 0; c < 4; c++)
#pragma unroll
      for (int nt = 0; nt < 3; nt++)
        bc2[c][nt] = *(const half8*)&w2t_s[(nt * 16 + l15) * 132 + c * 32 + quad * 8];
    int mi = 0;
    for (int mt = wave; mt < 9; mt += 4, mi++) {
      const int mA = mt * 16 + l15;
      const int ppA = mA >> 2, dA = mA & 3;
      const int y2 = 2 * (ppA / 6) + (dA >> 1);
      const int x2 = 2 * (ppA % 6) + (dA & 1);
      const int rb = ((y2 + ky) * 14 + x2) * 40;
#pragma unroll
      for (int c = 0; c < 4; c++) {
        const half8 af = *(const half8*)&h1_s[rb + c * 32 + quad * 8];
#pragma unroll
        for (int nt = 0; nt < 3; nt++)
          acc2[mi][nt] = __builtin_amdgcn_mfma_f32_16x16x32_f16(af, bc2[c][nt], acc2[mi][nt], 0, 0, 0);
      }
    }
  }

  // ---- pool conv2 in registers, stage emb, write out ----
  _Float16* h2s = x_s;   // x_s dead after conv1
  {
    int mi = 0;
    for (int mt = wave; mt < 9; mt += 4, mi++) {
      const int ppC = mt * 4 + quad;
#pragma unroll
      for (int nt = 0; nt < 3; nt++) {
        const int oc = nt * 16 + l15;
        float v = fmaxf(fmaxf(acc2[mi][nt][0], acc2[mi][nt][1]),
                        fmaxf(acc2[mi][nt][2], acc2[mi][nt][3])) + b2[oc];
        v = fmaxf(v, 0.f);
        h2s[oc * 36 + ppC] = (_Float16)v;
      }
    }
  }
  __syncthreads();
  {
    half8* dst = (half8*)(emb + (size_t)n * 1728);
    const half8* src = (const half8*)h2s;
    for (int i = tid; i < 216; i += 256) dst[i] = src[i];
  }
}

// ---------------------------------------------------------------------------
// fp32 -> fp16 cast (n multiple of 4)
// ---------------------------------------------------------------------------
__global__ void cast_f2h(const float* __restrict__ src, _Float16* __restrict__ dst, int n) {
  const int i = (blockIdx.x * 256 + threadIdx.x) * 4;
  if (i < n) {
    const float4 v = *(const float4*)(src + i);
    _Float16 o0 = (_Float16)v.x, o1 = (_Float16)v.y, o2 = (_Float16)v.z, o3 = (_Float16)v.w;
    ushort4 pk;
    pk.x = __builtin_bit_cast(unsigned short, o0);
    pk.y = __builtin_bit_cast(unsigned short, o1);
    pk.z = __builtin_bit_cast(unsigned short, o2);
    pk.w = __builtin_bit_cast(unsigned short, o3);
    *(ushort4*)(dst + i) = pk;
  }
}

// ---------------------------------------------------------------------------
// fp16 MFMA GEMM: C[m,n] = act( sum_k A[m,k]*B[n,k] + bias[n] )
// BM=128, BN=64, BK=64, 256 threads (4 waves), wave tile 64x32 (4x2 MFMA tiles)
// ACT: 0=none 1=relu 2=tanh.  M%128==0, N%64==0, K%64==0.
// ---------------------------------------------------------------------------
template <int ACT>
__launch_bounds__(256)
__global__ void gemm_h(const _Float16* __restrict__ A, const _Float16* __restrict__ B,
                       const float* __restrict__ bias, _Float16* __restrict__ C,
                       int K, int lda, int ldb, int ldc) {
  __shared__ __align__(16) _Float16 As[128 * 72];
  __shared__ __align__(16) _Float16 Bs[64 * 72];
  const int tid = threadIdx.x;
  const int m0 = blockIdx.y * 128, n0 = blockIdx.x * 64;
  const int lane = tid & 63, wave = tid >> 6;
  const int quad = lane >> 4, l15 = lane & 15;
  const int wm = (wave >> 1) * 64, wn = (wave & 1) * 32;
  const int arow = tid >> 3, acol = (tid & 7) * 8;

  floatx4 acc[4][2];
#pragma unroll
  for (int i = 0; i < 4; i++)
#pragma unroll
    for (int j = 0; j < 2; j++)
#pragma unroll
      for (int r = 0; r < 4; r++) acc[i][j][r] = 0.f;

  for (int k0 = 0; k0 < K; k0 += 64) {
    half8 av[4], bv[2];
#pragma unroll
    for (int i = 0; i < 4; i++)
      av[i] = *(const half8*)&A[(size_t)(m0 + arow + 32 * i) * lda + k0 + acol];
#pragma unroll
    for (int i = 0; i < 2; i++)
      bv[i] = *(const half8*)&B[(size_t)(n0 + arow + 32 * i) * ldb + k0 + acol];
    __syncthreads();
#pragma unroll
    for (int i = 0; i < 4; i++) *(half8*)&As[(arow + 32 * i) * 72 + acol] = av[i];
#pragma unroll
    for (int i = 0; i < 2; i++) *(half8*)&Bs[(arow + 32 * i) * 72 + acol] = bv[i];
    __syncthreads();
#pragma unroll
    for (int ks = 0; ks < 64; ks += 32) {
      half8 af[4], bf[2];
#pragma unroll
      for (int mt = 0; mt < 4; mt++)
        af[mt] = *(const half8*)&As[(wm + mt * 16 + l15) * 72 + ks + quad * 8];
#pragma unroll
      for (int nt = 0; nt < 2; nt++)
        bf[nt] = *(const half8*)&Bs[(wn + nt * 16 + l15) * 72 + ks + quad * 8];
#pragma unroll
      for (int mt = 0; mt < 4; mt++)
#pragma unroll
        for (int nt = 0; nt < 2; nt++)
          acc[mt][nt] = __builtin_amdgcn_mfma_f32_16x16x32_f16(af[mt], bf[nt], acc[mt][nt], 0, 0, 0);
    }
  }

#pragma unroll
  for (int nt = 0; nt < 2; nt++) {
    const int col = n0 + wn + nt * 16 + l15;
    const float bcol = bias[col];
#pragma unroll
    for (int mt = 0; mt < 4; mt++) {
#pragma unroll
      for (int r = 0; r < 4; r++) {
        const int row = m0 + wm + mt * 16 + quad * 4 + r;
        float v = acc[mt][nt][r] + bcol;
        if (ACT == 1) v = fmaxf(v, 0.f);
        if (ACT == 2) v = tanhf(v);
        C[(size_t)row * ldc + col] = (_Float16)v;
      }
    }
  }
}

// ---------------------------------------------------------------------------
// Neighborhood attention: one wave per instance. <=8 grid neighbors.
// ---------------------------------------------------------------------------
__launch_bounds__(256)
__global__ void nbhd_k(_Float16* __restrict__ H2, const _Float16* __restrict__ T) {
  const int wid = (blockIdx.x * 256 + threadIdx.x) >> 6;
  const int lane = threadIdx.x & 63;
  const int r = wid >> 6, c = wid & 63;
  const _Float16* hi = H2 + (size_t)wid * 1024;
  float hreg[8];
#pragma unroll
  for (int u = 0; u < 8; u++) hreg[u] = (float)hi[u * 64 + lane];

  float sv[8];
  int jv[8];
  bool ok[8];
  int q = 0;
#pragma unroll
  for (int dr = -1; dr <= 1; dr++)
#pragma unroll
    for (int dc = -1; dc <= 1; dc++) {
      if (dr == 0 && dc == 0) continue;
      const int rr = r + dr, cc = c + dc;
      const bool v = (rr >= 0) && (rr < 64) && (cc >= 0) && (cc < 64);
      const int j = v ? (rr * 64 + cc) : wid;
      const _Float16* tj = T + (size_t)j * 512;
      float s = 0.f;
#pragma unroll
      for (int u = 0; u < 8; u++) s = fmaf(hreg[u], (float)tj[u * 64 + lane], s);
#pragma unroll
      for (int off = 32; off > 0; off >>= 1) s += __shfl_xor(s, off, 64);
      sv[q] = v ? s : -3.4e38f;
      jv[q] = j;
      ok[q] = v;
      q++;
    }

  float m = sv[0];
#pragma unroll
  for (int i = 1; i < 8; i++) m = fmaxf(m, sv[i]);
  float e[8], den = 0.f;
#pragma unroll
  for (int i = 0; i < 8; i++) {
    e[i] = ok[i] ? expf(sv[i] - m) : 0.f;
    den += e[i];
  }
  const float inv = 1.f / den;

  float outv[8];
#pragma unroll
  for (int u = 0; u < 8; u++) outv[u] = 0.f;
#pragma unroll
  for (int i = 0; i < 8; i++) {
    const float al = e[i] * inv;
    const _Float16* hj = H2 + (size_t)jv[i] * 1024;
#pragma unroll
    for (int u = 0; u < 8; u++) outv[u] = fmaf(al, (float)hj[u * 64 + lane], outv[u]);
  }
  _Float16* dst = H2 + (size_t)wid * 1024 + 512;
#pragma unroll
  for (int u = 0; u < 8; u++) dst[u * 64 + lane] = (_Float16)outv[u];
}

// ---------------------------------------------------------------------------
// tl[t,n] = P[n,:] . templates[t,:]
// ---------------------------------------------------------------------------
__launch_bounds__(256)
__global__ void templ_scores(const _Float16* __restrict__ P, const float* __restrict__ tmpl,
                             float* __restrict__ tl) {
  const int wid = (blockIdx.x * 256 + threadIdx.x) >> 6;
  const int lane = threadIdx.x & 63;
  const _Float16* p = P + (size_t)wid * 1024;
  float pr[16];
#pragma unroll
  for (int u = 0; u < 16; u++) pr[u] = (float)p[u * 64 + lane];
  for (int t = 0; t < 10; t++) {
    const float* tp = tmpl + t * 1024;
    float s = 0.f;
#pragma unroll
    for (int u = 0; u < 16; u++) s = fmaf(pr[u], tp[u * 64 + lane], s);
#pragma unroll
    for (int off = 32; off > 0; off >>= 1) s += __shfl_xor(s, off, 64);
    if (lane == 0) tl[t * NINST + wid] = s;
  }
}

// ---------------------------------------------------------------------------
// Per-template softmax over N=4096
// ---------------------------------------------------------------------------
__launch_bounds__(256)
__global__ void softmax_rows(const float* __restrict__ tl, float* __restrict__ betas) {
  const int t = blockIdx.x, tid = threadIdx.x;
  __shared__ float red[256];
  const float* row = tl + t * NINST;
  float m = -3.4e38f;
  for (int i = tid; i < NINST; i += 256) m = fmaxf(m, row[i]);
  red[tid] = m;
  __syncthreads();
  for (int s = 128; s > 0; s >>= 1) {
    if (tid < s) red[tid] = fmaxf(red[tid], red[tid + s]);
    __syncthreads();
  }
  m = red[0];
  __syncthreads();
  float sum = 0.f;
  for (int i = tid; i < NINST; i += 256) sum += expf(row[i] - m);
  red[tid] = sum;
  __syncthreads();
  for (int s = 128; s > 0; s >>= 1) {
    if (tid < s) red[tid] += red[tid + s];
    __syncthreads();
  }
  const float inv = 1.f / red[0];
  for (int i = tid; i < NINST; i += 256) betas[t * NINST + i] = expf(row[i] - m) * inv;
}

__global__ void zero_embs(float* __restrict__ embs) {
  for (int i = threadIdx.x; i < 10 * 1024; i += 256) embs[i] = 0.f;
}

// ---------------------------------------------------------------------------
// embs[t,k] += sum_{n in slice} betas[t,n] * H2h[n,k]
// ---------------------------------------------------------------------------
__launch_bounds__(256)
__global__ void embs_k(const float* __restrict__ betas, const _Float16* __restrict__ H2,
                       float* __restrict__ embs) {
  const int k = blockIdx.x * 256 + threadIdx.x;
  const int nbase = blockIdx.y * 256;
  float acc[10];
#pragma unroll
  for (int t = 0; t < 10; t++) acc[t] = 0.f;
  for (int n = nbase; n < nbase + 256; n++) {
    const float v = (float)H2[(size_t)n * 1024 + k];
#pragma unroll
    for (int t = 0; t < 10; t++) acc[t] = fmaf(betas[t * NINST + n], v, acc[t]);
  }
#pragma unroll
  for (int t = 0; t < 10; t++) atomicAdd(&embs[t * 1024 + k], acc[t]);
}

// ---------------------------------------------------------------------------
// Global attention tail
// ---------------------------------------------------------------------------
__launch_bounds__(256)
__global__ void ga_k(const float* __restrict__ embs_g, const float* __restrict__ ga1_w,
                     const float* __restrict__ ga1_b, const float* __restrict__ ga2_w,
                     const float* __restrict__ ga2_b, const float* __restrict__ cls_w,
                     const float* __restrict__ cls_b, float* __restrict__ out,
                     float* __restrict__ gammas_ws) {
  __shared__ __align__(16) float embs_s[10 * 1024];
  __shared__ float hh[10 * 128];
  __shared__ float red[256];
  __shared__ float g_s[10], gam_s[10];
  __shared__ float M_s[1024];
  const int tid = threadIdx.x;
  const int wave = tid >> 6, lane = tid & 63;

  for (int i = tid; i < 10240; i += 256) embs_s[i] = embs_g[i];
  __syncthreads();

  for (int j = 0; j < 32; j++) {
    const int d = wave * 32 + j;
    float wreg[16];
#pragma unroll
    for (int u = 0; u < 16; u++) wreg[u] = ga1_w[(size_t)d * 1024 + u * 64 + lane];
    const float bd = ga1_b[d];
    for (int t = 0; t < 10; t++) {
      float s = 0.f;
#pragma unroll
      for (int u = 0; u < 16; u++) s = fmaf(wreg[u], embs_s[t * 1024 + u * 64 + lane], s);
#pragma unroll
      for (int off = 32; off > 0; off >>= 1) s += __shfl_xor(s, off, 64);
      if (lane == 0) hh[t * 128 + d] = tanhf(s + bd);
    }
  }
  __syncthreads();

  if (wave == 0) {
    for (int t = 0; t < 10; t++) {
      float s = hh[t * 128 + lane] * ga2_w[lane] + hh[t * 128 + 64 + lane] * ga2_w[64 + lane];
#pragma unroll
      for (int off = 32; off > 0; off >>= 1) s += __shfl_xor(s, off, 64);
      if (lane == 0) g_s[t] = s + ga2_b[0];
    }
  }
  __syncthreads();

  if (tid == 0) {
    float m = g_s[0];
    for (int t = 1; t < 10; t++) m = fmaxf(m, g_s[t]);
    float sum = 0.f;
    for (int t = 0; t < 10; t++) sum += expf(g_s[t] - m);
    for (int t = 0; t < 10; t++) {
      gam_s[t] = expf(g_s[t] - m) / sum;
      gammas_ws[t] = gam_s[t];
    }
  }
  __syncthreads();

  for (int k = tid; k < 1024; k += 256) {
    float a = 0.f;
#pragma unroll
    for (int t = 0; t < 10; t++) a = fmaf(gam_s[t], embs_s[t * 1024 + k], a);
    M_s[k] = a;
  }
  __syncthreads();

  float part = 0.f;
  for (int k = tid; k < 1024; k += 256) part = fmaf(M_s[k], cls_w[k], part);
  red[tid] = part;
  __syncthreads();
  for (int s = 128; s > 0; s >>= 1) {
    if (tid < s) red[tid] += red[tid + s];
    __syncthreads();
  }
  if (tid == 0) {
    const float z = red[0] + cls_b[0];
    const float yp = 1.f / (1.f + expf(-z));
    out[0] = yp;
    out[1] = (yp >= 0.5f) ? 1.f : 0.f;
  }
}

// ---------------------------------------------------------------------------
// A[n] = sum_t gammas[t] * betas[t,n]
// ---------------------------------------------------------------------------
__launch_bounds__(256)
__global__ void a_k(const float* __restrict__ betas, const float* __restrict__ gam,
                    float* __restrict__ outA) {
  const int n = blockIdx.x * 256 + threadIdx.x;
  float a = 0.f;
#pragma unroll
  for (int t = 0; t < 10; t++) a = fmaf(gam[t], betas[t * NINST + n], a);
  outA[n] = a;
}

// ---------------------------------------------------------------------------
extern "C" void kernel_launch(void* const* d_in, const int* in_sizes, int n_in,
                              void* d_out, int out_size, void* d_ws, size_t ws_size,
                              hipStream_t stream) {
  const float* x       = (const float*)d_in[0];
  const float* w1      = (const float*)d_in[2];
  const float* b1      = (const float*)d_in[3];
  const float* w2      = (const float*)d_in[4];
  const float* b2      = (const float*)d_in[5];
  const float* fc1_w   = (const float*)d_in[6];
  const float* fc1_b   = (const float*)d_in[7];
  const float* fc2_w   = (const float*)d_in[8];
  const float* fc2_b   = (const float*)d_in[9];
  const float* nbr_w   = (const float*)d_in[10];
  const float* nbr_b   = (const float*)d_in[11];
  const float* tmpl    = (const float*)d_in[12];
  const float* proto_w = (const float*)d_in[13];
  const float* proto_b = (const float*)d_in[14];
  const float* ga1_w   = (const float*)d_in[15];
  const float* ga1_b   = (const float*)d_in[16];
  const float* ga2_w   = (const float*)d_in[17];
  const float* ga2_b   = (const float*)d_in[18];
  const float* cls_w   = (const float*)d_in[19];
  const float* cls_b   = (const float*)d_in[20];
  float* out = (float*)d_out;

  char* w = (char*)d_ws;
  _Float16* embh   = (_Float16*)w;  w += (size_t)4096 * 1728 * 2;
  _Float16* H1h    = (_Float16*)w;  w += (size_t)4096 * 512 * 2;
  _Float16* H2h    = (_Float16*)w;  w += (size_t)4096 * 1024 * 2;
  _Float16* TbH    = (_Float16*)w;  w += (size_t)4096 * 512 * 2;
  _Float16* PH     = (_Float16*)w;  w += (size_t)4096 * 1024 * 2;
  _Float16* fc1wH  = (_Float16*)w;  w += (size_t)512 * 1728 * 2;
  _Float16* fc2wH  = (_Float16*)w;  w += (size_t)512 * 512 * 2;
  _Float16* nbrwH  = (_Float16*)w;  w += (size_t)512 * 512 * 2;
  _Float16* protowH= (_Float16*)w;  w += (size_t)1024 * 1024 * 2;
  _Float16* xhT    = (_Float16*)w;  w += (size_t)4096 * 4096 * 2;   // x channel-last
  _Float16* w1tG   = (_Float16*)w;  w += (size_t)48 * 68 * 2;
  _Float16* w2tG   = (_Float16*)w;  w += (size_t)3 * 48 * 132 * 2;
  float* tl   = (float*)w;          w += (size_t)10 * NINST * 4;
  float* bet  = (float*)w;          w += (size_t)10 * NINST * 4;
  float* embs = (float*)w;          w += (size_t)10 * 1024 * 4;
  float* gam  = (float*)w;          w += 256;

  // input / weight transforms
  xform_x<<<16384, 256, 0, stream>>>(x, xhT);
  xform_w1<<<1, 256, 0, stream>>>(w1, w1tG);
  xform_w2<<<1, 256, 0, stream>>>(w2, w2tG);
  cast_f2h<<<(512 * 1728 / 4 + 255) / 256, 256, 0, stream>>>(fc1_w, fc1wH, 512 * 1728);
  cast_f2h<<<(512 * 512 / 4 + 255) / 256, 256, 0, stream>>>(fc2_w, fc2wH, 512 * 512);
  cast_f2h<<<(512 * 512 / 4 + 255) / 256, 256, 0, stream>>>(nbr_w, nbrwH, 512 * 512);
  cast_f2h<<<(1024 * 1024 / 4 + 255) / 256, 256, 0, stream>>>(proto_w, protowH, 1024 * 1024);

  conv_fused<<<NINST, 256, 0, stream>>>(xhT, w1tG, w2tG, b1, b2, embh);

  gemm_h<1><<<dim3(8, 32), 256, 0, stream>>>(embh, fc1wH, fc1_b, H1h, 1728, 1728, 1728, 512);
  gemm_h<1><<<dim3(8, 32), 256, 0, stream>>>(H1h, fc2wH, fc2_b, H2h, 512, 512, 512, 1024);
  gemm_h<2><<<dim3(8, 32), 256, 0, stream>>>(H2h, nbrwH, nbr_b, TbH, 512, 1024, 512, 512);
  nbhd_k<<<1024, 256, 0, stream>>>(H2h, TbH);
  gemm_h<2><<<dim3(16, 32), 256, 0, stream>>>(H2h, protowH, proto_b, PH, 1024, 1024, 1024, 1024);
  templ_scores<<<1024, 256, 0, stream>>>(PH, tmpl, tl);
  softmax_rows<<<10, 256, 0, stream>>>(tl, bet);
  zero_embs<<<1, 256, 0, stream>>>(embs);
  embs_k<<<dim3(4, 16), 256, 0, stream>>>(bet, H2h, embs);
  ga_k<<<1, 256, 0, stream>>>(embs, ga1_w, ga1_b, ga2_w, ga2_b, cls_w, cls_b, out, gam);
  a_k<<<16, 256, 0, stream>>>(bet, gam, out + 2);
}

// Round 6
// 583.416 us; speedup vs baseline: 8.6615x; 1.0597x over previous
//
#include <hip/hip_runtime.h>
#include <math.h>

#define NINST 4096

typedef _Float16 half8 __attribute__((ext_vector_type(8)));
typedef _Float16 half4 __attribute__((ext_vector_type(4)));
typedef float floatx4 __attribute__((ext_vector_type(4)));

// ---------------------------------------------------------------------------
// xform_w12: w1 (36,3,4,4) -> w1t [48 oc][64], k = ky*16+kx*4+ic
//            w2 (48,36,3,3) -> w2t [3 ky][48 oc][128], k = kx*40+ic (k<120)
// zero-padded elsewhere. One block.
// ---------------------------------------------------------------------------
__global__ void xform_w12(const float* __restrict__ w1, const float* __restrict__ w2,
                          _Float16* __restrict__ w1t, _Float16* __restrict__ w2t) {
  for (int i = threadIdx.x; i < 48 * 64; i += 256) {
    const int oc = i >> 6, k = i & 63;
    const int ky = k >> 4, r = k & 15, kx = r >> 2, ic = r & 3;
    float v = 0.f;
    if (oc < 36 && ic < 3) v = w1[((oc * 3 + ic) * 4 + ky) * 4 + kx];
    w1t[i] = (_Float16)v;
  }
  for (int i = threadIdx.x; i < 3 * 48 * 128; i += 256) {
    const int ky = i / 6144, r = i % 6144;
    const int oc = r >> 7, k = r & 127;
    float v = 0.f;
    if (k < 120) {
      const int kx = k / 40, ic = k % 40;
      if (ic < 36) v = w2[((oc * 36 + ic) * 3 + ky) * 3 + kx];
    }
    w2t[i] = (_Float16)v;
  }
}

// ---------------------------------------------------------------------------
// MFMA conv, one block per instance. Weight fragments come straight from
// global (L2-resident 12.6 KB + 6.1 KB) -> only 4 barriers per block.
// LDS: x_s 8KB (ch-last fp16, ic pad 4) + h1_s 15.7KB ([196 pix][40 ic]) = 23.4KB
// Pool-aligned m-map: m = window*4 + (dy*2+dx) -> C-quad regs = 2x2 pool window.
// ---------------------------------------------------------------------------
__launch_bounds__(256, 4)
__global__ void conv_fused(const float* __restrict__ x,
                           const _Float16* __restrict__ w1t_g,
                           const _Float16* __restrict__ w2t_g,
                           const float* __restrict__ b1, const float* __restrict__ b2,
                           _Float16* __restrict__ emb) {
  __shared__ __align__(16) _Float16 smem[11952];
  _Float16* x_s  = smem;            // 4096 halves (reused as h2 staging later)
  _Float16* h1_s = smem + 4096;     // 7856 = 196*40 + 16 pad

  const int n = blockIdx.x, tid = threadIdx.x;
  const int lane = tid & 63, wave = tid >> 6;
  const int quad = lane >> 4, l15 = lane & 15;

  // ---- conv1 weight fragments (global, L2) ----
  half8 bc[2][3];
#pragma unroll
  for (int c = 0; c < 2; c++)
#pragma unroll
    for (int nt = 0; nt < 3; nt++)
      bc[c][nt] = *(const half8*)&w1t_g[(nt * 16 + l15) * 64 + c * 32 + quad * 8];
  float bia[3];
#pragma unroll
  for (int nt = 0; nt < 3; nt++) {
    const int oc = nt * 16 + l15;
    bia[nt] = (oc < 36) ? b1[oc] : 0.f;
  }

  // ---- stage x: fp32 NCHW -> fp16 channel-last [1024 pix][4] ----
  {
    const float* xb = x + (size_t)n * 3072;
    for (int p = tid; p < 1024; p += 256) {
      half4 v;
      v[0] = (_Float16)__builtin_nontemporal_load(&xb[p]);
      v[1] = (_Float16)__builtin_nontemporal_load(&xb[1024 + p]);
      v[2] = (_Float16)__builtin_nontemporal_load(&xb[2048 + p]);
      v[3] = (_Float16)0.f;
      *(half4*)&x_s[p * 4] = v;
    }
    if (tid < 16) h1_s[7840 + tid] = (_Float16)0.f;
  }
  __syncthreads();

  // ---- conv1: M=784, N=48(36), K=64(48) -> h1 pooled+relu ----
  for (int mt = wave; mt < 49; mt += 4) {
    const int mA = mt * 16 + l15;
    const int ppA = mA >> 2, dA = mA & 3;
    const int yA = 2 * (ppA / 14) + (dA >> 1);
    const int xA = 2 * (ppA % 14) + (dA & 1);
    floatx4 a1[3];
#pragma unroll
    for (int nt = 0; nt < 3; nt++)
#pragma unroll
      for (int r = 0; r < 4; r++) a1[nt][r] = 0.f;
#pragma unroll
    for (int c = 0; c < 2; c++) {
      const int row = yA + c * 2 + (quad >> 1);
      const half8 af = *(const half8*)&x_s[row * 128 + xA * 4 + (quad & 1) * 8];
#pragma unroll
      for (int nt = 0; nt < 3; nt++)
        a1[nt] = __builtin_amdgcn_mfma_f32_16x16x32_f16(af, bc[c][nt], a1[nt], 0, 0, 0);
    }
    const int ppC = mt * 4 + quad;
#pragma unroll
    for (int nt = 0; nt < 3; nt++) {
      const int oc = nt * 16 + l15;
      float v = fmaxf(fmaxf(a1[nt][0], a1[nt][1]), fmaxf(a1[nt][2], a1[nt][3])) + bia[nt];
      v = fmaxf(v, 0.f);
      if (oc < 40) h1_s[ppC * 40 + oc] = (_Float16)v;  // oc 36..39 write zeros (pad)
    }
  }
  __syncthreads();   // h1 ready

  // ---- conv2: M=144, N=48, K=3ky x 128(120) ----
  floatx4 acc2[3][3];
#pragma unroll
  for (int i = 0; i < 3; i++)
#pragma unroll
    for (int j = 0; j < 3; j++)
#pragma unroll
      for (int r = 0; r < 4; r++) acc2[i][j][r] = 0.f;

  for (int ky = 0; ky < 3; ky++) {
    half8 bc2[4][3];
#pragma unroll
    for (int c = 0; c < 4; c++)
#pragma unroll
      for (int nt = 0; nt < 3; nt++)
        bc2[c][nt] = *(const half8*)&w2t_g[ky * 6144 + (nt * 16 + l15) * 128 + c * 32 + quad * 8];
    int mi = 0;
    for (int mt = wave; mt < 9; mt += 4, mi++) {
      const int mA = mt * 16 + l15;
      const int ppA = mA >> 2, dA = mA & 3;
      const int y2 = 2 * (ppA / 6) + (dA >> 1);
      const int x2 = 2 * (ppA % 6) + (dA & 1);
      const int rb = ((y2 + ky) * 14 + x2) * 40;
#pragma unroll
      for (int c = 0; c < 4; c++) {
        const half8 af = *(const half8*)&h1_s[rb + c * 32 + quad * 8];
#pragma unroll
        for (int nt = 0; nt < 3; nt++)
          acc2[mi][nt] = __builtin_amdgcn_mfma_f32_16x16x32_f16(af, bc2[c][nt], acc2[mi][nt], 0, 0, 0);
      }
    }
  }
  __syncthreads();   // all x_s/h1 reads done; reuse x_s as emb staging

  {
    _Float16* h2s = x_s;
    int mi = 0;
    for (int mt = wave; mt < 9; mt += 4, mi++) {
      const int ppC = mt * 4 + quad;
#pragma unroll
      for (int nt = 0; nt < 3; nt++) {
        const int oc = nt * 16 + l15;
        float v = fmaxf(fmaxf(acc2[mi][nt][0], acc2[mi][nt][1]),
                        fmaxf(acc2[mi][nt][2], acc2[mi][nt][3])) + b2[oc];
        v = fmaxf(v, 0.f);
        h2s[oc * 36 + ppC] = (_Float16)v;
      }
    }
  }
  __syncthreads();
  {
    half8* dst = (half8*)(emb + (size_t)n * 1728);
    const half8* src = (const half8*)x_s;
    for (int i = tid; i < 216; i += 256) dst[i] = src[i];
  }
}

// ---------------------------------------------------------------------------
// Fused fp32->fp16 weight casts (4 arrays, one dispatch). grid (1024, 4)
// ---------------------------------------------------------------------------
__global__ void cast_all(const float* __restrict__ s0, _Float16* __restrict__ d0, int n0,
                         const float* __restrict__ s1, _Float16* __restrict__ d1, int n1,
                         const float* __restrict__ s2, _Float16* __restrict__ d2, int n2,
                         const float* __restrict__ s3, _Float16* __restrict__ d3, int n3) {
  const float* src; _Float16* dst; int n;
  switch (blockIdx.y) {
    case 0: src = s0; dst = d0; n = n0; break;
    case 1: src = s1; dst = d1; n = n1; break;
    case 2: src = s2; dst = d2; n = n2; break;
    default: src = s3; dst = d3; n = n3; break;
  }
  const int i = (blockIdx.x * 256 + threadIdx.x) * 4;
  if (i < n) {
    const float4 v = *(const float4*)(src + i);
    half4 o;
    o[0] = (_Float16)v.x; o[1] = (_Float16)v.y; o[2] = (_Float16)v.z; o[3] = (_Float16)v.w;
    *(half4*)(dst + i) = o;
  }
}

// ---------------------------------------------------------------------------
// fp16 MFMA GEMM: C[m,n] = act( sum_k A[m,k]*B[n,k] + bias[n] )
// BM=64, BN=64, BK=64, 256 threads (4 waves), wave tile 32x32 (2x2 MFMA tiles)
// ACT: 0=none 1=relu 2=tanh.  M%64==0, N%64==0, K%64==0.
// ---------------------------------------------------------------------------
template <int ACT>
__launch_bounds__(256)
__global__ void gemm_h(const _Float16* __restrict__ A, const _Float16* __restrict__ B,
                       const float* __restrict__ bias, _Float16* __restrict__ C,
                       int K, int lda, int ldb, int ldc) {
  __shared__ __align__(16) _Float16 As[64 * 72];
  __shared__ __align__(16) _Float16 Bs[64 * 72];
  const int tid = threadIdx.x;
  const int m0 = blockIdx.y * 64, n0 = blockIdx.x * 64;
  const int lane = tid & 63, wave = tid >> 6;
  const int quad = lane >> 4, l15 = lane & 15;
  const int wm = (wave >> 1) * 32, wn = (wave & 1) * 32;
  const int arow = tid >> 2, acol = (tid & 3) * 16;   // 64 rows x 2 chunks

  floatx4 acc[2][2];
#pragma unroll
  for (int i = 0; i < 2; i++)
#pragma unroll
    for (int j = 0; j < 2; j++)
#pragma unroll
      for (int r = 0; r < 4; r++) acc[i][j][r] = 0.f;

  for (int k0 = 0; k0 < K; k0 += 64) {
    half8 av0 = *(const half8*)&A[(size_t)(m0 + arow) * lda + k0 + acol];
    half8 av1 = *(const half8*)&A[(size_t)(m0 + arow) * lda + k0 + acol + 8];
    half8 bv0 = *(const half8*)&B[(size_t)(n0 + arow) * ldb + k0 + acol];
    half8 bv1 = *(const half8*)&B[(size_t)(n0 + arow) * ldb + k0 + acol + 8];
    __syncthreads();
    *(half8*)&As[arow * 72 + acol] = av0;
    *(half8*)&As[arow * 72 + acol + 8] = av1;
    *(half8*)&Bs[arow * 72 + acol] = bv0;
    *(half8*)&Bs[arow * 72 + acol + 8] = bv1;
    __syncthreads();
#pragma unroll
    for (int ks = 0; ks < 64; ks += 32) {
      half8 af[2], bf[2];
#pragma unroll
      for (int mt = 0; mt < 2; mt++)
        af[mt] = *(const half8*)&As[(wm + mt * 16 + l15) * 72 + ks + quad * 8];
#pragma unroll
      for (int nt = 0; nt < 2; nt++)
        bf[nt] = *(const half8*)&Bs[(wn + nt * 16 + l15) * 72 + ks + quad * 8];
#pragma unroll
      for (int mt = 0; mt < 2; mt++)
#pragma unroll
        for (int nt = 0; nt < 2; nt++)
          acc[mt][nt] = __builtin_amdgcn_mfma_f32_16x16x32_f16(af[mt], bf[nt], acc[mt][nt], 0, 0, 0);
    }
  }

#pragma unroll
  for (int nt = 0; nt < 2; nt++) {
    const int col = n0 + wn + nt * 16 + l15;
    const float bcol = bias[col];
#pragma unroll
    for (int mt = 0; mt < 2; mt++) {
#pragma unroll
      for (int r = 0; r < 4; r++) {
        const int row = m0 + wm + mt * 16 + quad * 4 + r;
        float v = acc[mt][nt][r] + bcol;
        if (ACT == 1) v = fmaxf(v, 0.f);
        if (ACT == 2) v = tanhf(v);
        C[(size_t)row * ldc + col] = (_Float16)v;
      }
    }
  }
}

// ---------------------------------------------------------------------------
// Neighborhood attention: one wave per instance. <=8 grid neighbors.
// ---------------------------------------------------------------------------
__launch_bounds__(256)
__global__ void nbhd_k(_Float16* __restrict__ H2, const _Float16* __restrict__ T) {
  const int wid = (blockIdx.x * 256 + threadIdx.x) >> 6;
  const int lane = threadIdx.x & 63;
  const int r = wid >> 6, c = wid & 63;
  const _Float16* hi = H2 + (size_t)wid * 1024;
  float hreg[8];
#pragma unroll
  for (int u = 0; u < 8; u++) hreg[u] = (float)hi[u * 64 + lane];

  float sv[8];
  int jv[8];
  bool ok[8];
  int q = 0;
#pragma unroll
  for (int dr = -1; dr <= 1; dr++)
#pragma unroll
    for (int dc = -1; dc <= 1; dc++) {
      if (dr == 0 && dc == 0) continue;
      const int rr = r + dr, cc = c + dc;
      const bool v = (rr >= 0) && (rr < 64) && (cc >= 0) && (cc < 64);
      const int j = v ? (rr * 64 + cc) : wid;
      const _Float16* tj = T + (size_t)j * 512;
      float s = 0.f;
#pragma unroll
      for (int u = 0; u < 8; u++) s = fmaf(hreg[u], (float)tj[u * 64 + lane], s);
#pragma unroll
      for (int off = 32; off > 0; off >>= 1) s += __shfl_xor(s, off, 64);
      sv[q] = v ? s : -3.4e38f;
      jv[q] = j;
      ok[q] = v;
      q++;
    }

  float m = sv[0];
#pragma unroll
  for (int i = 1; i < 8; i++) m = fmaxf(m, sv[i]);
  float e[8], den = 0.f;
#pragma unroll
  for (int i = 0; i < 8; i++) {
    e[i] = ok[i] ? expf(sv[i] - m) : 0.f;
    den += e[i];
  }
  const float inv = 1.f / den;

  float outv[8];
#pragma unroll
  for (int u = 0; u < 8; u++) outv[u] = 0.f;
#pragma unroll
  for (int i = 0; i < 8; i++) {
    const float al = e[i] * inv;
    const _Float16* hj = H2 + (size_t)jv[i] * 1024;
#pragma unroll
    for (int u = 0; u < 8; u++) outv[u] = fmaf(al, (float)hj[u * 64 + lane], outv[u]);
  }
  _Float16* dst = H2 + (size_t)wid * 1024 + 512;
#pragma unroll
  for (int u = 0; u < 8; u++) dst[u * 64 + lane] = (_Float16)outv[u];
}

// ---------------------------------------------------------------------------
// tl[t,n] = P[n,:] . templates[t,:]
// ---------------------------------------------------------------------------
__launch_bounds__(256)
__global__ void templ_scores(const _Float16* __restrict__ P, const float* __restrict__ tmpl,
                             float* __restrict__ tl) {
  const int wid = (blockIdx.x * 256 + threadIdx.x) >> 6;
  const int lane = threadIdx.x & 63;
  const _Float16* p = P + (size_t)wid * 1024;
  float pr[16];
#pragma unroll
  for (int u = 0; u < 16; u++) pr[u] = (float)p[u * 64 + lane];
  for (int t = 0; t < 10; t++) {
    const float* tp = tmpl + t * 1024;
    float s = 0.f;
#pragma unroll
    for (int u = 0; u < 16; u++) s = fmaf(pr[u], tp[u * 64 + lane], s);
#pragma unroll
    for (int off = 32; off > 0; off >>= 1) s += __shfl_xor(s, off, 64);
    if (lane == 0) tl[t * NINST + wid] = s;
  }
}

// ---------------------------------------------------------------------------
// Per-template softmax over N=4096
// ---------------------------------------------------------------------------
__launch_bounds__(256)
__global__ void softmax_rows(const float* __restrict__ tl, float* __restrict__ betas) {
  const int t = blockIdx.x, tid = threadIdx.x;
  __shared__ float red[256];
  const float* row = tl + t * NINST;
  float m = -3.4e38f;
  for (int i = tid; i < NINST; i += 256) m = fmaxf(m, row[i]);
  red[tid] = m;
  __syncthreads();
  for (int s = 128; s > 0; s >>= 1) {
    if (tid < s) red[tid] = fmaxf(red[tid], red[tid + s]);
    __syncthreads();
  }
  m = red[0];
  __syncthreads();
  float sum = 0.f;
  for (int i = tid; i < NINST; i += 256) sum += expf(row[i] - m);
  red[tid] = sum;
  __syncthreads();
  for (int s = 128; s > 0; s >>= 1) {
    if (tid < s) red[tid] += red[tid + s];
    __syncthreads();
  }
  const float inv = 1.f / red[0];
  for (int i = tid; i < NINST; i += 256) betas[t * NINST + i] = expf(row[i] - m) * inv;
}

__global__ void zero_embs(float* __restrict__ embs) {
  for (int i = threadIdx.x; i < 10 * 1024; i += 256) embs[i] = 0.f;
}

// ---------------------------------------------------------------------------
// embs[t,k] += sum_{n in slice} betas[t,n] * H2h[n,k]
// ---------------------------------------------------------------------------
__launch_bounds__(256)
__global__ void embs_k(const float* __restrict__ betas, const _Float16* __restrict__ H2,
                       float* __restrict__ embs) {
  const int k = blockIdx.x * 256 + threadIdx.x;
  const int nbase = blockIdx.y * 256;
  float acc[10];
#pragma unroll
  for (int t = 0; t < 10; t++) acc[t] = 0.f;
  for (int n = nbase; n < nbase + 256; n++) {
    const float v = (float)H2[(size_t)n * 1024 + k];
#pragma unroll
    for (int t = 0; t < 10; t++) acc[t] = fmaf(betas[t * NINST + n], v, acc[t]);
  }
#pragma unroll
  for (int t = 0; t < 10; t++) atomicAdd(&embs[t * 1024 + k], acc[t]);
}

// ---------------------------------------------------------------------------
// Global attention tail
// ---------------------------------------------------------------------------
__launch_bounds__(256)
__global__ void ga_k(const float* __restrict__ embs_g, const float* __restrict__ ga1_w,
                     const float* __restrict__ ga1_b, const float* __restrict__ ga2_w,
                     const float* __restrict__ ga2_b, const float* __restrict__ cls_w,
                     const float* __restrict__ cls_b, float* __restrict__ out,
                     float* __restrict__ gammas_ws) {
  __shared__ __align__(16) float embs_s[10 * 1024];
  __shared__ float hh[10 * 128];
  __shared__ float red[256];
  __shared__ float g_s[10], gam_s[10];
  __shared__ float M_s[1024];
  const int tid = threadIdx.x;
  const int wave = tid >> 6, lane = tid & 63;

  for (int i = tid; i < 10240; i += 256) embs_s[i] = embs_g[i];
  __syncthreads();

  for (int j = 0; j < 32; j++) {
    const int d = wave * 32 + j;
    float wreg[16];
#pragma unroll
    for (int u = 0; u < 16; u++) wreg[u] = ga1_w[(size_t)d * 1024 + u * 64 + lane];
    const float bd = ga1_b[d];
    for (int t = 0; t < 10; t++) {
      float s = 0.f;
#pragma unroll
      for (int u = 0; u < 16; u++) s = fmaf(wreg[u], embs_s[t * 1024 + u * 64 + lane], s);
#pragma unroll
      for (int off = 32; off > 0; off >>= 1) s += __shfl_xor(s, off, 64);
      if (lane == 0) hh[t * 128 + d] = tanhf(s + bd);
    }
  }
  __syncthreads();

  if (wave == 0) {
    for (int t = 0; t < 10; t++) {
      float s = hh[t * 128 + lane] * ga2_w[lane] + hh[t * 128 + 64 + lane] * ga2_w[64 + lane];
#pragma unroll
      for (int off = 32; off > 0; off >>= 1) s += __shfl_xor(s, off, 64);
      if (lane == 0) g_s[t] = s + ga2_b[0];
    }
  }
  __syncthreads();

  if (tid == 0) {
    float m = g_s[0];
    for (int t = 1; t < 10; t++) m = fmaxf(m, g_s[t]);
    float sum = 0.f;
    for (int t = 0; t < 10; t++) sum += expf(g_s[t] - m);
    for (int t = 0; t < 10; t++) {
      gam_s[t] = expf(g_s[t] - m) / sum;
      gammas_ws[t] = gam_s[t];
    }
  }
  __syncthreads();

  for (int k = tid; k < 1024; k += 256) {
    float a = 0.f;
#pragma unroll
    for (int t = 0; t < 10; t++) a = fmaf(gam_s[t], embs_s[t * 1024 + k], a);
    M_s[k] = a;
  }
  __syncthreads();

  float part = 0.f;
  for (int k = tid; k < 1024; k += 256) part = fmaf(M_s[k], cls_w[k], part);
  red[tid] = part;
  __syncthreads();
  for (int s = 128; s > 0; s >>= 1) {
    if (tid < s) red[tid] += red[tid + s];
    __syncthreads();
  }
  if (tid == 0) {
    const float z = red[0] + cls_b[0];
    const float yp = 1.f / (1.f + expf(-z));
    out[0] = yp;
    out[1] = (yp >= 0.5f) ? 1.f : 0.f;
  }
}

// ---------------------------------------------------------------------------
// A[n] = sum_t gammas[t] * betas[t,n]
// ---------------------------------------------------------------------------
__launch_bounds__(256)
__global__ void a_k(const float* __restrict__ betas, const float* __restrict__ gam,
                    float* __restrict__ outA) {
  const int n = blockIdx.x * 256 + threadIdx.x;
  float a = 0.f;
#pragma unroll
  for (int t = 0; t < 10; t++) a = fmaf(gam[t], betas[t * NINST + n], a);
  outA[n] = a;
}

// ---------------------------------------------------------------------------
extern "C" void kernel_launch(void* const* d_in, const int* in_sizes, int n_in,
                              void* d_out, int out_size, void* d_ws, size_t ws_size,
                              hipStream_t stream) {
  const float* x       = (const float*)d_in[0];
  const float* w1      = (const float*)d_in[2];
  const float* b1      = (const float*)d_in[3];
  const float* w2      = (const float*)d_in[4];
  const float* b2      = (const float*)d_in[5];
  const float* fc1_w   = (const float*)d_in[6];
  const float* fc1_b   = (const float*)d_in[7];
  const float* fc2_w   = (const float*)d_in[8];
  const float* fc2_b   = (const float*)d_in[9];
  const float* nbr_w   = (const float*)d_in[10];
  const float* nbr_b   = (const float*)d_in[11];
  const float* tmpl    = (const float*)d_in[12];
  const float* proto_w = (const float*)d_in[13];
  const float* proto_b = (const float*)d_in[14];
  const float* ga1_w   = (const float*)d_in[15];
  const float* ga1_b   = (const float*)d_in[16];
  const float* ga2_w   = (const float*)d_in[17];
  const float* ga2_b   = (const float*)d_in[18];
  const float* cls_w   = (const float*)d_in[19];
  const float* cls_b   = (const float*)d_in[20];
  float* out = (float*)d_out;

  char* w = (char*)d_ws;
  _Float16* embh   = (_Float16*)w;  w += (size_t)4096 * 1728 * 2;
  _Float16* H1h    = (_Float16*)w;  w += (size_t)4096 * 512 * 2;
  _Float16* H2h    = (_Float16*)w;  w += (size_t)4096 * 1024 * 2;
  _Float16* TbH    = (_Float16*)w;  w += (size_t)4096 * 512 * 2;
  _Float16* PH     = (_Float16*)w;  w += (size_t)4096 * 1024 * 2;
  _Float16* fc1wH  = (_Float16*)w;  w += (size_t)512 * 1728 * 2;
  _Float16* fc2wH  = (_Float16*)w;  w += (size_t)512 * 512 * 2;
  _Float16* nbrwH  = (_Float16*)w;  w += (size_t)512 * 512 * 2;
  _Float16* protowH= (_Float16*)w;  w += (size_t)1024 * 1024 * 2;
  _Float16* w1tG   = (_Float16*)w;  w += (size_t)48 * 64 * 2;
  _Float16* w2tG   = (_Float16*)w;  w += (size_t)3 * 48 * 128 * 2;
  float* tl   = (float*)w;          w += (size_t)10 * NINST * 4;
  float* bet  = (float*)w;          w += (size_t)10 * NINST * 4;
  float* embs = (float*)w;          w += (size_t)10 * 1024 * 4;
  float* gam  = (float*)w;          w += 256;

  xform_w12<<<1, 256, 0, stream>>>(w1, w2, w1tG, w2tG);
  cast_all<<<dim3(1024, 4), 256, 0, stream>>>(fc1_w, fc1wH, 512 * 1728,
                                              fc2_w, fc2wH, 512 * 512,
                                              nbr_w, nbrwH, 512 * 512,
                                              proto_w, protowH, 1024 * 1024);

  conv_fused<<<NINST, 256, 0, stream>>>(x, w1tG, w2tG, b1, b2, embh);

  gemm_h<1><<<dim3(8, 64), 256, 0, stream>>>(embh, fc1wH, fc1_b, H1h, 1728, 1728, 1728, 512);
  gemm_h<1><<<dim3(8, 64), 256, 0, stream>>>(H1h, fc2wH, fc2_b, H2h, 512, 512, 512, 1024);
  gemm_h<2><<<dim3(8, 64), 256, 0, stream>>>(H2h, nbrwH, nbr_b, TbH, 512, 1024, 512, 512);
  nbhd_k<<<1024, 256, 0, stream>>>(H2h, TbH);
  gemm_h<2><<<dim3(16, 64), 256, 0, stream>>>(H2h, protowH, proto_b, PH, 1024, 1024, 1024, 1024);
  templ_scores<<<1024, 256, 0, stream>>>(PH, tmpl, tl);
  softmax_rows<<<10, 256, 0, stream>>>(tl, bet);
  zero_embs<<<1, 256, 0, stream>>>(embs);
  embs_k<<<dim3(4, 16), 256, 0, stream>>>(bet, H2h, embs);
  ga_k<<<1, 256, 0, stream>>>(embs, ga1_w, ga1_b, ga2_w, ga2_b, cls_w, cls_b, out, gam);
  a_k<<<16, 256, 0, stream>>>(bet, gam, out + 2);
}